// Round 1
// baseline (788.922 us; speedup 1.0000x reference)
//
#include <hip/hip_runtime.h>
#include <hip/hip_bf16.h>

// Shapes (fixed by the problem): B=4, S=8192, D_MODEL=1024, NHEAD=16, D_K=64,
// D_CHUNK=128, C=64 chunks. M = B*S = 32768 rows for all GEMMs, K=N=1024.

typedef __attribute__((ext_vector_type(8))) short short8;   // 8 bf16 (MFMA A/B frag)
typedef __attribute__((ext_vector_type(4))) float f32x4;    // MFMA C/D frag
typedef __attribute__((ext_vector_type(4))) unsigned short us4;

__device__ __forceinline__ unsigned short f2bf(float f) {
  unsigned u = __float_as_uint(f);
  u += 0x7fffu + ((u >> 16) & 1u);          // RNE round to bf16
  return (unsigned short)(u >> 16);
}

__device__ __forceinline__ void gload16(const void* g, void* l) {
  __builtin_amdgcn_global_load_lds((const __attribute__((address_space(1))) void*)g,
                                   (__attribute__((address_space(3))) void*)l, 16, 0, 0);
}

// ---------------- fp32 -> bf16 (weights) ----------------
__global__ void f2b_kernel(const float* __restrict__ in, unsigned short* __restrict__ out, int n) {
  int i = (blockIdx.x * 256 + threadIdx.x) * 4;
  if (i >= n) return;
  f32x4 x = *(const f32x4*)(in + i);
  us4 o;
  #pragma unroll
  for (int j = 0; j < 4; ++j) o[j] = f2bf(x[j]);
  *(us4*)(out + i) = o;
}

// ---------------- GEMM: C[M,1024] = A[M,1024] * B[1024,1024]^T + bias ----------------
// B is row-major [n][k] (i.e. W as given: out = x @ W.T), so both operands are
// K-contiguous. 128x128 tile, BK=32, 4 waves each owning a 64x64 sub-tile.
template<bool A_F32, bool C_F32>
__global__ __launch_bounds__(256)
void gemm_bt(const void* __restrict__ Ap, const unsigned short* __restrict__ Bp,
             const float* __restrict__ bias, void* __restrict__ Cp) {
  constexpr int BK = 32;
  const int tid = threadIdx.x;
  const int lane = tid & 63, wave = tid >> 6;
  const int lg = lane >> 4, li = lane & 15;
  const int bn = blockIdx.x, bm = blockIdx.y;
  const long arow0 = (long)bm * 128;
  const int bcol0 = bn * 128;
  const int wr = wave >> 1, wc = wave & 1;

  constexpr int AB = A_F32 ? 4 : 2;
  __shared__ __align__(16) unsigned char As[128 * BK * AB];
  __shared__ __align__(16) unsigned char Bs[128 * BK * 2];

  f32x4 acc[4][4];
  #pragma unroll
  for (int m = 0; m < 4; ++m)
    #pragma unroll
    for (int n = 0; n < 4; ++n) acc[m][n] = (f32x4){0.f, 0.f, 0.f, 0.f};

  for (int k0 = 0; k0 < 1024; k0 += BK) {
    // ---- stage A tile [128][BK] ----
    if constexpr (A_F32) {
      const float* A = (const float*)Ap;
      #pragma unroll
      for (int it = 0; it < 4; ++it) {
        int slot = it * 256 + tid;                 // 16B slots, lane-contiguous
        int row = slot >> 3, col = (slot & 7) * 4; // 8 slots/row of 32 floats
        gload16(A + (arow0 + row) * 1024 + k0 + col, As + slot * 16);
      }
    } else {
      const unsigned short* A = (const unsigned short*)Ap;
      #pragma unroll
      for (int it = 0; it < 2; ++it) {
        int slot = it * 256 + tid;
        int row = slot >> 2, col = (slot & 3) * 8; // 4 slots/row of 32 bf16
        gload16(A + (arow0 + row) * 1024 + k0 + col, As + slot * 16);
      }
    }
    // ---- stage B tile [128][BK] bf16 ----
    #pragma unroll
    for (int it = 0; it < 2; ++it) {
      int slot = it * 256 + tid;
      int row = slot >> 2, col = (slot & 3) * 8;
      gload16(Bp + (long)(bcol0 + row) * 1024 + k0 + col, Bs + slot * 16);
    }
    __syncthreads();   // compiler drains vmcnt before s_barrier

    short8 af[4], bf[4];
    #pragma unroll
    for (int m = 0; m < 4; ++m) {
      int row = wr * 64 + m * 16 + li;
      if constexpr (A_F32) {
        const float* p = (const float*)As + row * BK + lg * 8;
        f32x4 u0 = *(const f32x4*)p, u1 = *(const f32x4*)(p + 4);
        #pragma unroll
        for (int j = 0; j < 4; ++j) {
          af[m][j]     = (short)f2bf(u0[j]);
          af[m][4 + j] = (short)f2bf(u1[j]);
        }
      } else {
        af[m] = *(const short8*)((const unsigned short*)As + row * BK + lg * 8);
      }
    }
    #pragma unroll
    for (int n = 0; n < 4; ++n) {
      int row = wc * 64 + n * 16 + li;
      bf[n] = *(const short8*)((const unsigned short*)Bs + row * BK + lg * 8);
    }
    #pragma unroll
    for (int m = 0; m < 4; ++m)
      #pragma unroll
      for (int n = 0; n < 4; ++n)
        acc[m][n] = __builtin_amdgcn_mfma_f32_16x16x32_bf16(af[m], bf[n], acc[m][n], 0, 0, 0);
    __syncthreads();
  }

  // ---- epilogue: C/D layout col=lane&15, row=(lane>>4)*4+reg ----
  #pragma unroll
  for (int n = 0; n < 4; ++n) {
    int col = bcol0 + wc * 64 + n * 16 + li;
    float bv = bias[col];
    #pragma unroll
    for (int m = 0; m < 4; ++m) {
      long row = arow0 + wr * 64 + m * 16 + lg * 4;
      #pragma unroll
      for (int r = 0; r < 4; ++r) {
        float v = acc[m][n][r] + bv;
        if constexpr (C_F32) ((float*)Cp)[(row + r) * 1024 + col] = v;
        else ((unsigned short*)Cp)[(row + r) * 1024 + col] = f2bf(v);
      }
    }
  }
}

// ---------------- block-local attention per (b,h,c) ----------------
// Q/K/V tiles are [128 rows][64 cols] slices of the projected [32768][1024]
// bf16 buffers (row = b*8192 + c*128 + p, col = h*64 + d).
__global__ __launch_bounds__(256)
void attn_kernel(const unsigned short* __restrict__ Qp, const unsigned short* __restrict__ Kp,
                 const unsigned short* __restrict__ Vp, unsigned short* __restrict__ Cc) {
  const int bid = blockIdx.x;
  const int c = bid & 63, h = (bid >> 6) & 15, b = bid >> 10;
  const int tid = threadIdx.x;
  const int lane = tid & 63, wave = tid >> 6;
  const int lg = lane >> 4, li = lane & 15;

  __shared__ __align__(16) unsigned short Qs[128 * 64];
  __shared__ __align__(16) unsigned short Ks[128 * 64];
  __shared__ __align__(16) unsigned short Vs[128 * 64];
  __shared__ __align__(16) unsigned short Ps[4][32 * 128];

  const long base = ((long)(b * 8192 + c * 128)) * 1024 + h * 64;
  #pragma unroll
  for (int it = 0; it < 4; ++it) {
    int slot = it * 256 + tid;
    int row = slot >> 3, col = (slot & 7) * 8;     // 8 slots per 64-elem row
    long g = base + (long)row * 1024 + col;
    gload16(Qp + g, (unsigned char*)Qs + slot * 16);
    gload16(Kp + g, (unsigned char*)Ks + slot * 16);
    gload16(Vp + g, (unsigned char*)Vs + slot * 16);
  }
  __syncthreads();

  // ---- scores: wave w computes rows [w*32, w*32+32) x all 128 key cols ----
  f32x4 sc[2][8];
  #pragma unroll
  for (int m = 0; m < 2; ++m)
    #pragma unroll
    for (int n = 0; n < 8; ++n) sc[m][n] = (f32x4){0.f, 0.f, 0.f, 0.f};

  short8 qf[2][2];
  #pragma unroll
  for (int m = 0; m < 2; ++m)
    #pragma unroll
    for (int ks = 0; ks < 2; ++ks)
      qf[m][ks] = *(const short8*)(Qs + (wave * 32 + m * 16 + li) * 64 + ks * 32 + lg * 8);

  #pragma unroll
  for (int n = 0; n < 8; ++n) {
    short8 kf0 = *(const short8*)(Ks + (n * 16 + li) * 64 + lg * 8);
    short8 kf1 = *(const short8*)(Ks + (n * 16 + li) * 64 + 32 + lg * 8);
    #pragma unroll
    for (int m = 0; m < 2; ++m) {
      sc[m][n] = __builtin_amdgcn_mfma_f32_16x16x32_bf16(qf[m][0], kf0, sc[m][n], 0, 0, 0);
      sc[m][n] = __builtin_amdgcn_mfma_f32_16x16x32_bf16(qf[m][1], kf1, sc[m][n], 0, 0, 0);
    }
  }

  // ---- softmax: row = m*16 + lg*4 + r lives in 16 lanes (same lg), 8 frags ----
  #pragma unroll
  for (int m = 0; m < 2; ++m)
    #pragma unroll
    for (int r = 0; r < 4; ++r) {
      float mx = sc[m][0][r];
      #pragma unroll
      for (int n = 1; n < 8; ++n) mx = fmaxf(mx, sc[m][n][r]);
      #pragma unroll
      for (int d = 1; d < 16; d <<= 1) mx = fmaxf(mx, __shfl_xor(mx, d));
      float sum = 0.f;
      #pragma unroll
      for (int n = 0; n < 8; ++n) {
        float p = __expf((sc[m][n][r] - mx) * 0.125f);  // scale 1/sqrt(64)
        sc[m][n][r] = p;
        sum += p;
      }
      #pragma unroll
      for (int d = 1; d < 16; d <<= 1) sum += __shfl_xor(sum, d);
      float rinv = 1.f / sum;
      #pragma unroll
      for (int n = 0; n < 8; ++n) sc[m][n][r] *= rinv;
    }

  // ---- P -> LDS (bf16) so it can be re-read in MFMA A-operand layout ----
  #pragma unroll
  for (int m = 0; m < 2; ++m)
    #pragma unroll
    for (int n = 0; n < 8; ++n)
      #pragma unroll
      for (int r = 0; r < 4; ++r)
        Ps[wave][(m * 16 + lg * 4 + r) * 128 + n * 16 + li] = f2bf(sc[m][n][r]);
  __syncthreads();

  // ---- O = P @ V : [32,128] x [128,64] ----
  f32x4 oc[2][4];
  #pragma unroll
  for (int m = 0; m < 2; ++m)
    #pragma unroll
    for (int n = 0; n < 4; ++n) oc[m][n] = (f32x4){0.f, 0.f, 0.f, 0.f};

  #pragma unroll
  for (int ks = 0; ks < 4; ++ks) {
    short8 vf[4];                    // B-operand: col=li (d), k strided 64 in LDS
    #pragma unroll
    for (int n = 0; n < 4; ++n)
      #pragma unroll
      for (int j = 0; j < 8; ++j)
        vf[n][j] = (short)Vs[(ks * 32 + lg * 8 + j) * 64 + n * 16 + li];
    #pragma unroll
    for (int m = 0; m < 2; ++m) {
      short8 pf = *(const short8*)(Ps[wave] + (m * 16 + li) * 128 + ks * 32 + lg * 8);
      #pragma unroll
      for (int n = 0; n < 4; ++n)
        oc[m][n] = __builtin_amdgcn_mfma_f32_16x16x32_bf16(pf, vf[n], oc[m][n], 0, 0, 0);
    }
  }

  // ---- torch-faithful scrambled concat write ----
  #pragma unroll
  for (int m = 0; m < 2; ++m)
    #pragma unroll
    for (int n = 0; n < 4; ++n)
      #pragma unroll
      for (int r = 0; r < 4; ++r) {
        int p = wave * 32 + m * 16 + lg * 4 + r;   // position within chunk
        int d = n * 16 + li;                       // head dim
        int s = c * 128 + h * 8 + (p >> 4);
        int colo = (p & 15) * 64 + d;
        Cc[((long)(b * 8192 + s)) * 1024 + colo] = f2bf(oc[m][n][r]);
      }
}

extern "C" void kernel_launch(void* const* d_in, const int* in_sizes, int n_in,
                              void* d_out, int out_size, void* d_ws, size_t ws_size,
                              hipStream_t stream) {
  (void)in_sizes; (void)n_in; (void)out_size; (void)ws_size;
  const float* q  = (const float*)d_in[0];
  const float* k  = (const float*)d_in[1];
  const float* v  = (const float*)d_in[2];
  const float* WQ = (const float*)d_in[3];
  const float* bQ = (const float*)d_in[4];
  const float* WK = (const float*)d_in[5];
  const float* bK = (const float*)d_in[6];
  const float* WV = (const float*)d_in[7];
  const float* bV = (const float*)d_in[8];
  const float* WO = (const float*)d_in[9];
  const float* bO = (const float*)d_in[10];

  // ws layout: Qp | Kp | Vp | concat (each 32768*1024 bf16 = 64MB) | 4 bf16 weights
  const size_t MN = 32768ull * 1024ull;
  unsigned short* Qp  = (unsigned short*)d_ws;
  unsigned short* Kp  = Qp + MN;
  unsigned short* Vp  = Kp + MN;
  unsigned short* Cc  = Vp + MN;
  unsigned short* WQb = Cc + MN;
  unsigned short* WKb = WQb + (1 << 20);
  unsigned short* WVb = WKb + (1 << 20);
  unsigned short* WOb = WVb + (1 << 20);

  f2b_kernel<<<1024, 256, 0, stream>>>(WQ, WQb, 1 << 20);
  f2b_kernel<<<1024, 256, 0, stream>>>(WK, WKb, 1 << 20);
  f2b_kernel<<<1024, 256, 0, stream>>>(WV, WVb, 1 << 20);
  f2b_kernel<<<1024, 256, 0, stream>>>(WO, WOb, 1 << 20);

  dim3 gg(8, 256);   // x = N/128 (consecutive blocks share the A panel), y = M/128
  gemm_bt<true,  false><<<gg, 256, 0, stream>>>(q, WQb, bQ, Qp);
  gemm_bt<true,  false><<<gg, 256, 0, stream>>>(k, WKb, bK, Kp);
  gemm_bt<true,  false><<<gg, 256, 0, stream>>>(v, WVb, bV, Vp);

  attn_kernel<<<4096, 256, 0, stream>>>(Qp, Kp, Vp, Cc);

  gemm_bt<false, true><<<gg, 256, 0, stream>>>(Cc, WOb, bO, (float*)d_out);
}

// Round 2
// 711.764 us; speedup vs baseline: 1.1084x; 1.1084x over previous
//
#include <hip/hip_runtime.h>
#include <hip/hip_bf16.h>

// Shapes (fixed): B=4, S=8192, D_MODEL=1024, NHEAD=16, D_K=64, D_CHUNK=128,
// C=64 chunks. M = B*S = 32768 rows for all GEMMs, K=N=1024.

typedef __attribute__((ext_vector_type(8))) short short8;   // 8 bf16 (MFMA A/B frag)
typedef __attribute__((ext_vector_type(4))) float f32x4;    // MFMA C/D frag
typedef __attribute__((ext_vector_type(4))) unsigned short us4;

__device__ __forceinline__ unsigned short f2bf(float f) {
  unsigned u = __float_as_uint(f);
  u += 0x7fffu + ((u >> 16) & 1u);          // RNE round to bf16
  return (unsigned short)(u >> 16);
}

__device__ __forceinline__ void gload16(const void* g, void* l) {
  __builtin_amdgcn_global_load_lds((const __attribute__((address_space(1))) void*)g,
                                   (__attribute__((address_space(3))) void*)l, 16, 0, 0);
}

// ---------------- fp32 -> bf16 (weights, small) ----------------
__global__ void f2b_kernel(const float* __restrict__ in, unsigned short* __restrict__ out, int n) {
  int i = (blockIdx.x * 256 + threadIdx.x) * 4;
  if (i >= n) return;
  f32x4 x = *(const f32x4*)(in + i);
  us4 o;
  #pragma unroll
  for (int j = 0; j < 4; ++j) o[j] = f2bf(x[j]);
  *(us4*)(out + i) = o;
}

// ---------------- fp32 -> bf16 (activations, 32 MB each) ----------------
// Memory-bound: 32B read + 16B write per lane per iter, grid-stride.
__global__ __launch_bounds__(256)
void cvt_kernel(const float* __restrict__ in, unsigned short* __restrict__ out, int n) {
  int stride = gridDim.x * 256 * 8;
  for (int i = (blockIdx.x * 256 + threadIdx.x) * 8; i < n; i += stride) {
    f32x4 a = *(const f32x4*)(in + i);
    f32x4 b = *(const f32x4*)(in + i + 4);
    short8 o;
    #pragma unroll
    for (int j = 0; j < 4; ++j) {
      o[j]     = (short)f2bf(a[j]);
      o[4 + j] = (short)f2bf(b[j]);
    }
    *(short8*)(out + i) = o;
  }
}

// ---------------- GEMM: C[M,1024] = A[M,1024](bf16) * B[1024,1024]^T + bias ----
// m97 structure: 128x128 tile, BK=32, 4 waves each owning a 64x64 sub-tile,
// global_load_lds width=16 staging, 16x16x32 bf16 MFMA.
template<bool C_F32>
__global__ __launch_bounds__(256)
void gemm_bt(const unsigned short* __restrict__ Ap, const unsigned short* __restrict__ Bp,
             const float* __restrict__ bias, void* __restrict__ Cp) {
  constexpr int BK = 32;
  const int tid = threadIdx.x;
  const int lane = tid & 63, wave = tid >> 6;
  const int lg = lane >> 4, li = lane & 15;

  // XCD swizzle (m157; nwg = 2048, divisible by 8 -> bijective): the 8
  // N-blocks sharing one A panel run consecutively on ONE XCD -> panel is
  // fetched into that XCD's L2 once instead of 8 HBM/L3 trips.
  const int nwg = gridDim.x * gridDim.y;           // 2048
  const int orig = blockIdx.y * gridDim.x + blockIdx.x;
  const int wg = (orig & 7) * (nwg >> 3) + (orig >> 3);
  const int bn = wg & 7, bm = wg >> 3;

  const long arow0 = (long)bm * 128;
  const int bcol0 = bn * 128;
  const int wr = wave >> 1, wc = wave & 1;

  __shared__ __align__(16) unsigned short As[128 * BK];
  __shared__ __align__(16) unsigned short Bs[128 * BK];

  f32x4 acc[4][4];
  #pragma unroll
  for (int m = 0; m < 4; ++m)
    #pragma unroll
    for (int n = 0; n < 4; ++n) acc[m][n] = (f32x4){0.f, 0.f, 0.f, 0.f};

  for (int k0 = 0; k0 < 1024; k0 += BK) {
    #pragma unroll
    for (int it = 0; it < 2; ++it) {
      int slot = it * 256 + tid;
      int row = slot >> 2, col = (slot & 3) * 8;   // 4 slots/row of 32 bf16
      gload16(Ap + (arow0 + row) * 1024 + k0 + col, (unsigned char*)As + slot * 16);
      gload16(Bp + (long)(bcol0 + row) * 1024 + k0 + col, (unsigned char*)Bs + slot * 16);
    }
    __syncthreads();   // compiler drains vmcnt before s_barrier

    short8 af[4], bf[4];
    #pragma unroll
    for (int m = 0; m < 4; ++m)
      af[m] = *(const short8*)(As + (wr * 64 + m * 16 + li) * BK + lg * 8);
    #pragma unroll
    for (int n = 0; n < 4; ++n)
      bf[n] = *(const short8*)(Bs + (wc * 64 + n * 16 + li) * BK + lg * 8);

    #pragma unroll
    for (int m = 0; m < 4; ++m)
      #pragma unroll
      for (int n = 0; n < 4; ++n)
        acc[m][n] = __builtin_amdgcn_mfma_f32_16x16x32_bf16(af[m], bf[n], acc[m][n], 0, 0, 0);
    __syncthreads();
  }

  // ---- epilogue: C/D layout col=lane&15, row=(lane>>4)*4+reg ----
  #pragma unroll
  for (int n = 0; n < 4; ++n) {
    int col = bcol0 + wc * 64 + n * 16 + li;
    float bv = bias[col];
    #pragma unroll
    for (int m = 0; m < 4; ++m) {
      long row = arow0 + wr * 64 + m * 16 + lg * 4;
      #pragma unroll
      for (int r = 0; r < 4; ++r) {
        float v = acc[m][n][r] + bv;
        if constexpr (C_F32) ((float*)Cp)[(row + r) * 1024 + col] = v;
        else ((unsigned short*)Cp)[(row + r) * 1024 + col] = f2bf(v);
      }
    }
  }
}

// ---------------- block-local attention per (b,h,c) ----------------
// Q/K/V tiles are [128 rows][64 cols] slices of the projected [32768][1024]
// bf16 buffers (row = b*8192 + c*128 + p, col = h*64 + d).
__global__ __launch_bounds__(256)
void attn_kernel(const unsigned short* __restrict__ Qp, const unsigned short* __restrict__ Kp,
                 const unsigned short* __restrict__ Vp, unsigned short* __restrict__ Cc) {
  const int bid = blockIdx.x;
  const int c = bid & 63, h = (bid >> 6) & 15, b = bid >> 10;
  const int tid = threadIdx.x;
  const int lane = tid & 63, wave = tid >> 6;
  const int lg = lane >> 4, li = lane & 15;

  __shared__ __align__(16) unsigned short Qs[128 * 64];
  __shared__ __align__(16) unsigned short Ks[128 * 64];
  __shared__ __align__(16) unsigned short Vs[128 * 64];
  __shared__ __align__(16) unsigned short Ps[4][32 * 128];

  const long base = ((long)(b * 8192 + c * 128)) * 1024 + h * 64;
  #pragma unroll
  for (int it = 0; it < 4; ++it) {
    int slot = it * 256 + tid;
    int row = slot >> 3, col = (slot & 7) * 8;     // 8 slots per 64-elem row
    long g = base + (long)row * 1024 + col;
    gload16(Qp + g, (unsigned char*)Qs + slot * 16);
    gload16(Kp + g, (unsigned char*)Ks + slot * 16);
    gload16(Vp + g, (unsigned char*)Vs + slot * 16);
  }
  __syncthreads();

  // ---- scores: wave w computes rows [w*32, w*32+32) x all 128 key cols ----
  f32x4 sc[2][8];
  #pragma unroll
  for (int m = 0; m < 2; ++m)
    #pragma unroll
    for (int n = 0; n < 8; ++n) sc[m][n] = (f32x4){0.f, 0.f, 0.f, 0.f};

  short8 qf[2][2];
  #pragma unroll
  for (int m = 0; m < 2; ++m)
    #pragma unroll
    for (int ks = 0; ks < 2; ++ks)
      qf[m][ks] = *(const short8*)(Qs + (wave * 32 + m * 16 + li) * 64 + ks * 32 + lg * 8);

  #pragma unroll
  for (int n = 0; n < 8; ++n) {
    short8 kf0 = *(const short8*)(Ks + (n * 16 + li) * 64 + lg * 8);
    short8 kf1 = *(const short8*)(Ks + (n * 16 + li) * 64 + 32 + lg * 8);
    #pragma unroll
    for (int m = 0; m < 2; ++m) {
      sc[m][n] = __builtin_amdgcn_mfma_f32_16x16x32_bf16(qf[m][0], kf0, sc[m][n], 0, 0, 0);
      sc[m][n] = __builtin_amdgcn_mfma_f32_16x16x32_bf16(qf[m][1], kf1, sc[m][n], 0, 0, 0);
    }
  }

  // ---- softmax: row = m*16 + lg*4 + r lives in 16 lanes (same lg) ----
  #pragma unroll
  for (int m = 0; m < 2; ++m)
    #pragma unroll
    for (int r = 0; r < 4; ++r) {
      float mx = sc[m][0][r];
      #pragma unroll
      for (int n = 1; n < 8; ++n) mx = fmaxf(mx, sc[m][n][r]);
      #pragma unroll
      for (int d = 1; d < 16; d <<= 1) mx = fmaxf(mx, __shfl_xor(mx, d));
      float sum = 0.f;
      #pragma unroll
      for (int n = 0; n < 8; ++n) {
        float p = __expf((sc[m][n][r] - mx) * 0.125f);  // scale 1/sqrt(64)
        sc[m][n][r] = p;
        sum += p;
      }
      #pragma unroll
      for (int d = 1; d < 16; d <<= 1) sum += __shfl_xor(sum, d);
      float rinv = 1.f / sum;
      #pragma unroll
      for (int n = 0; n < 8; ++n) sc[m][n][r] *= rinv;
    }

  // ---- P -> LDS (bf16) so it can be re-read in MFMA A-operand layout ----
  #pragma unroll
  for (int m = 0; m < 2; ++m)
    #pragma unroll
    for (int n = 0; n < 8; ++n)
      #pragma unroll
      for (int r = 0; r < 4; ++r)
        Ps[wave][(m * 16 + lg * 4 + r) * 128 + n * 16 + li] = f2bf(sc[m][n][r]);
  __syncthreads();

  // ---- O = P @ V : [32,128] x [128,64] ----
  f32x4 oc[2][4];
  #pragma unroll
  for (int m = 0; m < 2; ++m)
    #pragma unroll
    for (int n = 0; n < 4; ++n) oc[m][n] = (f32x4){0.f, 0.f, 0.f, 0.f};

  #pragma unroll
  for (int ks = 0; ks < 4; ++ks) {
    short8 vf[4];                    // B-operand: col=li (d), k strided 64 in LDS
    #pragma unroll
    for (int n = 0; n < 4; ++n)
      #pragma unroll
      for (int j = 0; j < 8; ++j)
        vf[n][j] = (short)Vs[(ks * 32 + lg * 8 + j) * 64 + n * 16 + li];
    #pragma unroll
    for (int m = 0; m < 2; ++m) {
      short8 pf = *(const short8*)(Ps[wave] + (m * 16 + li) * 128 + ks * 32 + lg * 8);
      #pragma unroll
      for (int n = 0; n < 4; ++n)
        oc[m][n] = __builtin_amdgcn_mfma_f32_16x16x32_bf16(pf, vf[n], oc[m][n], 0, 0, 0);
    }
  }

  // ---- torch-faithful scrambled concat write ----
  #pragma unroll
  for (int m = 0; m < 2; ++m)
    #pragma unroll
    for (int n = 0; n < 4; ++n)
      #pragma unroll
      for (int r = 0; r < 4; ++r) {
        int p = wave * 32 + m * 16 + lg * 4 + r;   // position within chunk
        int d = n * 16 + li;                       // head dim
        int s = c * 128 + h * 8 + (p >> 4);
        int colo = (p & 15) * 64 + d;
        Cc[((long)(b * 8192 + s)) * 1024 + colo] = f2bf(oc[m][n][r]);
      }
}

extern "C" void kernel_launch(void* const* d_in, const int* in_sizes, int n_in,
                              void* d_out, int out_size, void* d_ws, size_t ws_size,
                              hipStream_t stream) {
  (void)in_sizes; (void)n_in; (void)out_size; (void)ws_size;
  const float* q  = (const float*)d_in[0];
  const float* k  = (const float*)d_in[1];
  const float* v  = (const float*)d_in[2];
  const float* WQ = (const float*)d_in[3];
  const float* bQ = (const float*)d_in[4];
  const float* WK = (const float*)d_in[5];
  const float* bK = (const float*)d_in[6];
  const float* WV = (const float*)d_in[7];
  const float* bV = (const float*)d_in[8];
  const float* WO = (const float*)d_in[9];
  const float* bO = (const float*)d_in[10];

  // ws layout: qb | kb | vb | Qp | Kp | Vp | concat (each 64MB bf16) + weights
  const size_t MN = 32768ull * 1024ull;
  unsigned short* qb  = (unsigned short*)d_ws;
  unsigned short* kb  = qb + MN;
  unsigned short* vb  = kb + MN;
  unsigned short* Qp  = vb + MN;
  unsigned short* Kp  = Qp + MN;
  unsigned short* Vp  = Kp + MN;
  unsigned short* Cc  = Vp + MN;
  unsigned short* WQb = Cc + MN;
  unsigned short* WKb = WQb + (1 << 20);
  unsigned short* WVb = WKb + (1 << 20);
  unsigned short* WOb = WVb + (1 << 20);

  f2b_kernel<<<1024, 256, 0, stream>>>(WQ, WQb, 1 << 20);
  f2b_kernel<<<1024, 256, 0, stream>>>(WK, WKb, 1 << 20);
  f2b_kernel<<<1024, 256, 0, stream>>>(WV, WVb, 1 << 20);
  f2b_kernel<<<1024, 256, 0, stream>>>(WO, WOb, 1 << 20);

  const int NA = (int)MN;  // 2^25 elements per activation
  cvt_kernel<<<2048, 256, 0, stream>>>(q, qb, NA);
  cvt_kernel<<<2048, 256, 0, stream>>>(k, kb, NA);
  cvt_kernel<<<2048, 256, 0, stream>>>(v, vb, NA);

  dim3 gg(8, 256);   // 2048 blocks; swizzled inside the kernel
  gemm_bt<false><<<gg, 256, 0, stream>>>(qb, WQb, bQ, Qp);
  gemm_bt<false><<<gg, 256, 0, stream>>>(kb, WKb, bK, Kp);
  gemm_bt<false><<<gg, 256, 0, stream>>>(vb, WVb, bV, Vp);

  attn_kernel<<<4096, 256, 0, stream>>>(Qp, Kp, Vp, Cc);

  gemm_bt<true><<<gg, 256, 0, stream>>>(Cc, WOb, bO, (float*)d_out);
}

// Round 4
// 667.490 us; speedup vs baseline: 1.1819x; 1.0663x over previous
//
#include <hip/hip_runtime.h>
#include <hip/hip_bf16.h>

// Shapes (fixed): B=4, S=8192, D_MODEL=1024, NHEAD=16, D_K=64, D_CHUNK=128,
// C=64 chunks. M = B*S = 32768 rows for all GEMMs, K=N=1024.

typedef __attribute__((ext_vector_type(8))) short short8;   // 8 bf16 (MFMA A/B frag)
typedef __attribute__((ext_vector_type(4))) float f32x4;    // MFMA C/D frag
typedef __attribute__((ext_vector_type(4))) unsigned short us4;

__device__ __forceinline__ unsigned short f2bf(float f) {
  unsigned u = __float_as_uint(f);
  u += 0x7fffu + ((u >> 16) & 1u);          // RNE round to bf16
  return (unsigned short)(u >> 16);
}

__device__ __forceinline__ void gload16(const void* g, void* l) {
  __builtin_amdgcn_global_load_lds((const __attribute__((address_space(1))) void*)g,
                                   (__attribute__((address_space(3))) void*)l, 16, 0, 0);
}

// ---------------- fp32 -> bf16 (weights, small) ----------------
__global__ void f2b_kernel(const float* __restrict__ in, unsigned short* __restrict__ out, int n) {
  int i = (blockIdx.x * 256 + threadIdx.x) * 4;
  if (i >= n) return;
  f32x4 x = *(const f32x4*)(in + i);
  us4 o;
  #pragma unroll
  for (int j = 0; j < 4; ++j) o[j] = f2bf(x[j]);
  *(us4*)(out + i) = o;
}

// ---------------- fp32 -> bf16 (q,k,v activations in one dispatch) ----------------
__global__ __launch_bounds__(256)
void cvt3_kernel(const float* __restrict__ i0, const float* __restrict__ i1,
                 const float* __restrict__ i2, unsigned short* __restrict__ o0,
                 unsigned short* __restrict__ o1, unsigned short* __restrict__ o2, int n) {
  const int z = blockIdx.z;
  const float* in = z == 0 ? i0 : z == 1 ? i1 : i2;
  unsigned short* out = z == 0 ? o0 : z == 1 ? o1 : o2;
  int stride = gridDim.x * 256 * 8;
  for (int i = (blockIdx.x * 256 + threadIdx.x) * 8; i < n; i += stride) {
    f32x4 a = *(const f32x4*)(in + i);
    f32x4 b = *(const f32x4*)(in + i + 4);
    short8 o;
    #pragma unroll
    for (int j = 0; j < 4; ++j) {
      o[j]     = (short)f2bf(a[j]);
      o[4 + j] = (short)f2bf(b[j]);
    }
    *(short8*)(out + i) = o;
  }
}

// ---------------- GEMM core: C[M,1024] = A[M,1024](bf16) * B[1024,1024]^T + bias ----
// 128x128 tile, BK=64, 4 waves each owning a 64x64 sub-tile.
// Race-free minimum 2-phase pipeline (T3 catalog recipe): issue next tile's
// global_load_lds EARLY (before ds_read+MFMA of current tile), then ONE
// full-drain __syncthreads() per K-tile. Double-buffered LDS.
// T2 bank-conflict fix: LDS dest stays LINEAR (global_load_lds requirement);
// XOR swizzle g^(row&7) applied to the GLOBAL source granule and identically
// on the ds_read address (same involution both sides — rule 21).
template<bool C_F32>
__device__ __forceinline__ void gemm_core(const unsigned short* __restrict__ Ap,
                                          const unsigned short* __restrict__ Bp,
                                          const float* __restrict__ bias,
                                          void* __restrict__ Cp) {
  constexpr int BK = 64, NT = 16;
  const int tid = threadIdx.x;
  const int lane = tid & 63, wave = tid >> 6;
  const int lg = lane >> 4, li = lane & 15;

  // XCD swizzle (m157; nwg = 2048, divisible by 8 -> bijective).
  const int orig = blockIdx.y * 8 + blockIdx.x;
  const int wg = (orig & 7) * 256 + (orig >> 3);
  const int bn = wg & 7, bm = wg >> 3;

  const long arow0 = (long)bm * 128;
  const int bcol0 = bn * 128;
  const int wr = wave >> 1, wc = wave & 1;

  __shared__ __align__(16) unsigned short As[2][128 * BK];
  __shared__ __align__(16) unsigned short Bs[2][128 * BK];

  f32x4 acc[4][4];
  #pragma unroll
  for (int m = 0; m < 4; ++m)
    #pragma unroll
    for (int n = 0; n < 4; ++n) acc[m][n] = (f32x4){0.f, 0.f, 0.f, 0.f};

  // Stage K-tile t: 128 rows x 64 bf16 = 8 granules of 16B per row per operand;
  // 256 threads x 4 iters; 8 gload16 per thread.
  auto stage = [&](int t) {
    const int k0 = t * BK;
    unsigned short* Asb = As[t & 1];
    unsigned short* Bsb = Bs[t & 1];
    #pragma unroll
    for (int it = 0; it < 4; ++it) {
      int s = it * 256 + tid;
      int row = s >> 3;
      int eg = ((s & 7) ^ (row & 7)) * 8;   // pre-swizzled source granule
      gload16(Ap + (arow0 + row) * 1024 + k0 + eg, (unsigned char*)Asb + s * 16);
      gload16(Bp + (long)(bcol0 + row) * 1024 + k0 + eg, (unsigned char*)Bsb + s * 16);
    }
  };

  stage(0);
  __syncthreads();                         // prologue: vmcnt(0) drain + barrier

  for (int t = 0; t < NT; ++t) {
    if (t + 1 < NT) stage(t + 1);          // issue next tile; lands under compute

    const unsigned short* Asb = As[t & 1];
    const unsigned short* Bsb = Bs[t & 1];
    short8 af[4][2], bfr[4][2];
    #pragma unroll
    for (int m = 0; m < 4; ++m) {
      int row = wr * 64 + m * 16 + li;     // row&7 == li&7
      #pragma unroll
      for (int kk = 0; kk < 2; ++kk)
        af[m][kk] = *(const short8*)(Asb + row * BK + (((kk * 4 + lg) ^ (li & 7)) * 8));
    }
    #pragma unroll
    for (int n = 0; n < 4; ++n) {
      int row = wc * 64 + n * 16 + li;
      #pragma unroll
      for (int kk = 0; kk < 2; ++kk)
        bfr[n][kk] = *(const short8*)(Bsb + row * BK + (((kk * 4 + lg) ^ (li & 7)) * 8));
    }
    #pragma unroll
    for (int kk = 0; kk < 2; ++kk)
      #pragma unroll
      for (int m = 0; m < 4; ++m)
        #pragma unroll
        for (int n = 0; n < 4; ++n)
          acc[m][n] = __builtin_amdgcn_mfma_f32_16x16x32_bf16(af[m][kk], bfr[n][kk], acc[m][n], 0, 0, 0);

    __syncthreads();                       // full drain: tile t+1 staged, buf[t&1] free
  }

  // ---- epilogue: C/D layout col=lane&15, row=(lane>>4)*4+reg ----
  #pragma unroll
  for (int n = 0; n < 4; ++n) {
    int col = bcol0 + wc * 64 + n * 16 + li;
    float bv = bias[col];
    #pragma unroll
    for (int m = 0; m < 4; ++m) {
      long row = arow0 + wr * 64 + m * 16 + lg * 4;
      #pragma unroll
      for (int r = 0; r < 4; ++r) {
        float v = acc[m][n][r] + bv;
        if constexpr (C_F32) ((float*)Cp)[(row + r) * 1024 + col] = v;
        else ((unsigned short*)Cp)[(row + r) * 1024 + col] = f2bf(v);
      }
    }
  }
}

// Three projections batched via blockIdx.z (q,k,v are DIFFERENT A matrices).
__global__ __launch_bounds__(256)
void gemm_proj(const unsigned short* __restrict__ A0, const unsigned short* __restrict__ A1,
               const unsigned short* __restrict__ A2,
               const unsigned short* __restrict__ B0, const unsigned short* __restrict__ B1,
               const unsigned short* __restrict__ B2,
               const float* __restrict__ b0, const float* __restrict__ b1,
               const float* __restrict__ b2,
               unsigned short* __restrict__ C0, unsigned short* __restrict__ C1,
               unsigned short* __restrict__ C2) {
  const int z = blockIdx.z;
  const unsigned short* Ap = z == 0 ? A0 : z == 1 ? A1 : A2;
  const unsigned short* Bp = z == 0 ? B0 : z == 1 ? B1 : B2;
  const float* bias        = z == 0 ? b0 : z == 1 ? b1 : b2;
  unsigned short* Cp       = z == 0 ? C0 : z == 1 ? C1 : C2;
  gemm_core<false>(Ap, Bp, bias, Cp);
}

__global__ __launch_bounds__(256)
void gemm_out(const unsigned short* __restrict__ Ap, const unsigned short* __restrict__ Bp,
              const float* __restrict__ bias, float* __restrict__ Cp) {
  gemm_core<true>(Ap, Bp, bias, Cp);
}

// ---------------- block-local attention per (b,h,c) ----------------
__global__ __launch_bounds__(256)
void attn_kernel(const unsigned short* __restrict__ Qp, const unsigned short* __restrict__ Kp,
                 const unsigned short* __restrict__ Vp, unsigned short* __restrict__ Cc) {
  const int bid = blockIdx.x;
  const int c = bid & 63, h = (bid >> 6) & 15, b = bid >> 10;
  const int tid = threadIdx.x;
  const int lane = tid & 63, wave = tid >> 6;
  const int lg = lane >> 4, li = lane & 15;

  __shared__ __align__(16) unsigned short Qs[128 * 64];
  __shared__ __align__(16) unsigned short Ks[128 * 64];
  __shared__ __align__(16) unsigned short Vs[128 * 64];
  __shared__ __align__(16) unsigned short Ps[4][32 * 128];

  const long base = ((long)(b * 8192 + c * 128)) * 1024 + h * 64;
  #pragma unroll
  for (int it = 0; it < 4; ++it) {
    int slot = it * 256 + tid;
    int row = slot >> 3, col = (slot & 7) * 8;
    long g = base + (long)row * 1024 + col;
    gload16(Qp + g, (unsigned char*)Qs + slot * 16);
    gload16(Kp + g, (unsigned char*)Ks + slot * 16);
    gload16(Vp + g, (unsigned char*)Vs + slot * 16);
  }
  __syncthreads();

  // ---- scores: wave w computes rows [w*32, w*32+32) x all 128 key cols ----
  f32x4 sc[2][8];
  #pragma unroll
  for (int m = 0; m < 2; ++m)
    #pragma unroll
    for (int n = 0; n < 8; ++n) sc[m][n] = (f32x4){0.f, 0.f, 0.f, 0.f};

  short8 qf[2][2];
  #pragma unroll
  for (int m = 0; m < 2; ++m)
    #pragma unroll
    for (int ks = 0; ks < 2; ++ks)
      qf[m][ks] = *(const short8*)(Qs + (wave * 32 + m * 16 + li) * 64 + ks * 32 + lg * 8);

  #pragma unroll
  for (int n = 0; n < 8; ++n) {
    short8 kf0 = *(const short8*)(Ks + (n * 16 + li) * 64 + lg * 8);
    short8 kf1 = *(const short8*)(Ks + (n * 16 + li) * 64 + 32 + lg * 8);
    #pragma unroll
    for (int m = 0; m < 2; ++m) {
      sc[m][n] = __builtin_amdgcn_mfma_f32_16x16x32_bf16(qf[m][0], kf0, sc[m][n], 0, 0, 0);
      sc[m][n] = __builtin_amdgcn_mfma_f32_16x16x32_bf16(qf[m][1], kf1, sc[m][n], 0, 0, 0);
    }
  }

  // ---- softmax: row = m*16 + lg*4 + r lives in 16 lanes (same lg) ----
  #pragma unroll
  for (int m = 0; m < 2; ++m)
    #pragma unroll
    for (int r = 0; r < 4; ++r) {
      float mx = sc[m][0][r];
      #pragma unroll
      for (int n = 1; n < 8; ++n) mx = fmaxf(mx, sc[m][n][r]);
      #pragma unroll
      for (int d = 1; d < 16; d <<= 1) mx = fmaxf(mx, __shfl_xor(mx, d));
      float sum = 0.f;
      #pragma unroll
      for (int n = 0; n < 8; ++n) {
        float p = __expf((sc[m][n][r] - mx) * 0.125f);  // scale 1/sqrt(64)
        sc[m][n][r] = p;
        sum += p;
      }
      #pragma unroll
      for (int d = 1; d < 16; d <<= 1) sum += __shfl_xor(sum, d);
      float rinv = 1.f / sum;
      #pragma unroll
      for (int n = 0; n < 8; ++n) sc[m][n][r] *= rinv;
    }

  // ---- P -> LDS (bf16) ----
  #pragma unroll
  for (int m = 0; m < 2; ++m)
    #pragma unroll
    for (int n = 0; n < 8; ++n)
      #pragma unroll
      for (int r = 0; r < 4; ++r)
        Ps[wave][(m * 16 + lg * 4 + r) * 128 + n * 16 + li] = f2bf(sc[m][n][r]);
  __syncthreads();

  // ---- O = P @ V : [32,128] x [128,64] ----
  f32x4 oc[2][4];
  #pragma unroll
  for (int m = 0; m < 2; ++m)
    #pragma unroll
    for (int n = 0; n < 4; ++n) oc[m][n] = (f32x4){0.f, 0.f, 0.f, 0.f};

  #pragma unroll
  for (int ks = 0; ks < 4; ++ks) {
    short8 vf[4];
    #pragma unroll
    for (int n = 0; n < 4; ++n)
      #pragma unroll
      for (int j = 0; j < 8; ++j)
        vf[n][j] = (short)Vs[(ks * 32 + lg * 8 + j) * 64 + n * 16 + li];
    #pragma unroll
    for (int m = 0; m < 2; ++m) {
      short8 pf = *(const short8*)(Ps[wave] + (m * 16 + li) * 128 + ks * 32 + lg * 8);
      #pragma unroll
      for (int n = 0; n < 4; ++n)
        oc[m][n] = __builtin_amdgcn_mfma_f32_16x16x32_bf16(pf, vf[n], oc[m][n], 0, 0, 0);
    }
  }

  // ---- torch-faithful scrambled concat write ----
  #pragma unroll
  for (int m = 0; m < 2; ++m)
    #pragma unroll
    for (int n = 0; n < 4; ++n)
      #pragma unroll
      for (int r = 0; r < 4; ++r) {
        int p = wave * 32 + m * 16 + lg * 4 + r;
        int d = n * 16 + li;
        int s = c * 128 + h * 8 + (p >> 4);
        int colo = (p & 15) * 64 + d;
        Cc[((long)(b * 8192 + s)) * 1024 + colo] = f2bf(oc[m][n][r]);
      }
}

extern "C" void kernel_launch(void* const* d_in, const int* in_sizes, int n_in,
                              void* d_out, int out_size, void* d_ws, size_t ws_size,
                              hipStream_t stream) {
  (void)in_sizes; (void)n_in; (void)out_size; (void)ws_size;
  const float* q  = (const float*)d_in[0];
  const float* k  = (const float*)d_in[1];
  const float* v  = (const float*)d_in[2];
  const float* WQ = (const float*)d_in[3];
  const float* bQ = (const float*)d_in[4];
  const float* WK = (const float*)d_in[5];
  const float* bK = (const float*)d_in[6];
  const float* WV = (const float*)d_in[7];
  const float* bV = (const float*)d_in[8];
  const float* WO = (const float*)d_in[9];
  const float* bO = (const float*)d_in[10];

  // ws layout: qb | kb | vb | Qp | Kp | Vp | Cc (each 64MB bf16) + weights
  const size_t MN = 32768ull * 1024ull;
  unsigned short* qb  = (unsigned short*)d_ws;
  unsigned short* kb  = qb + MN;
  unsigned short* vb  = kb + MN;
  unsigned short* Qp  = vb + MN;
  unsigned short* Kp  = Qp + MN;
  unsigned short* Vp  = Kp + MN;
  unsigned short* Cc  = Vp + MN;
  unsigned short* WQb = Cc + MN;
  unsigned short* WKb = WQb + (1 << 20);
  unsigned short* WVb = WKb + (1 << 20);
  unsigned short* WOb = WVb + (1 << 20);

  f2b_kernel<<<1024, 256, 0, stream>>>(WQ, WQb, 1 << 20);
  f2b_kernel<<<1024, 256, 0, stream>>>(WK, WKb, 1 << 20);
  f2b_kernel<<<1024, 256, 0, stream>>>(WV, WVb, 1 << 20);
  f2b_kernel<<<1024, 256, 0, stream>>>(WO, WOb, 1 << 20);

  const int NA = (int)MN;
  dim3 gc(1024, 1, 3);
  cvt3_kernel<<<gc, 256, 0, stream>>>(q, k, v, qb, kb, vb, NA);

  dim3 gp(8, 256, 3);   // 3 projections batched; 2048 blocks per z-slice
  gemm_proj<<<gp, 256, 0, stream>>>(qb, kb, vb, WQb, WKb, WVb, bQ, bK, bV, Qp, Kp, Vp);

  attn_kernel<<<4096, 256, 0, stream>>>(Qp, Kp, Vp, Cc);

  dim3 go(8, 256);
  gemm_out<<<go, 256, 0, stream>>>(Cc, WOb, bO, (float*)d_out);
}

// Round 5
// 613.928 us; speedup vs baseline: 1.2850x; 1.0872x over previous
//
#include <hip/hip_runtime.h>
#include <hip/hip_bf16.h>

// Shapes (fixed): B=4, S=8192, D_MODEL=1024, NHEAD=16, D_K=64, D_CHUNK=128,
// C=64 chunks. M = B*S = 32768 rows for all GEMMs, K=N=1024.

typedef __attribute__((ext_vector_type(8))) short short8;   // 8 bf16 (MFMA A/B frag)
typedef __attribute__((ext_vector_type(4))) float f32x4;    // MFMA C/D frag
typedef __attribute__((ext_vector_type(4))) unsigned short us4;

__device__ __forceinline__ unsigned short f2bf(float f) {
  unsigned u = __float_as_uint(f);
  u += 0x7fffu + ((u >> 16) & 1u);          // RNE round to bf16
  return (unsigned short)(u >> 16);
}

__device__ __forceinline__ void gload16(const void* g, void* l) {
  __builtin_amdgcn_global_load_lds((const __attribute__((address_space(1))) void*)g,
                                   (__attribute__((address_space(3))) void*)l, 16, 0, 0);
}

// ---------------- fp32 -> bf16 (4 weight matrices, one dispatch) ----------------
__global__ void f2b4_kernel(const float* __restrict__ i0, const float* __restrict__ i1,
                            const float* __restrict__ i2, const float* __restrict__ i3,
                            unsigned short* __restrict__ o0, unsigned short* __restrict__ o1,
                            unsigned short* __restrict__ o2, unsigned short* __restrict__ o3,
                            int n) {
  const int z = blockIdx.z;
  const float* in = z == 0 ? i0 : z == 1 ? i1 : z == 2 ? i2 : i3;
  unsigned short* out = z == 0 ? o0 : z == 1 ? o1 : z == 2 ? o2 : o3;
  int i = (blockIdx.x * 256 + threadIdx.x) * 4;
  if (i >= n) return;
  f32x4 x = *(const f32x4*)(in + i);
  us4 o;
  #pragma unroll
  for (int j = 0; j < 4; ++j) o[j] = f2bf(x[j]);
  *(us4*)(out + i) = o;
}

// ---------------- fp32 -> bf16 (q,k,v activations in one dispatch) ----------------
__global__ __launch_bounds__(256)
void cvt3_kernel(const float* __restrict__ i0, const float* __restrict__ i1,
                 const float* __restrict__ i2, unsigned short* __restrict__ o0,
                 unsigned short* __restrict__ o1, unsigned short* __restrict__ o2, int n) {
  const int z = blockIdx.z;
  const float* in = z == 0 ? i0 : z == 1 ? i1 : i2;
  unsigned short* out = z == 0 ? o0 : z == 1 ? o1 : o2;
  int stride = gridDim.x * 256 * 8;
  for (int i = (blockIdx.x * 256 + threadIdx.x) * 8; i < n; i += stride) {
    f32x4 a = *(const f32x4*)(in + i);
    f32x4 b = *(const f32x4*)(in + i + 4);
    short8 o;
    #pragma unroll
    for (int j = 0; j < 4; ++j) {
      o[j]     = (short)f2bf(a[j]);
      o[4 + j] = (short)f2bf(b[j]);
    }
    *(short8*)(out + i) = o;
  }
}

// ---------------- GEMM core: C[M,1024] = A[M,1024](bf16) * B[1024,1024]^T + bias ----
// 256x256 tile, BK=64, 512 threads = 8 waves (2M x 4N), per-wave output 128x64.
// This geometry makes MFMA (64 x ~5cyc) the longest per-tile pole vs 24
// ds_read_b128 (~288cyc issue) — vs 0.5 reads/MFMA at the old 128² tile.
//
// Counted-vmcnt pipeline (2 LDS buffers, 2 tiles in flight):
//   per tile t: [ds_read frags -> MFMA] ; s_barrier (all waves consumed
//   buf[t&1], every ds_read was delivered before its consuming MFMA which
//   precedes the barrier) ; stage(t+2) into buf[t&1] ; vmcnt(8) (drains tile
//   t+1's 8 loads only — tile t+2's 8 stay in flight across the barrier) ;
//   s_barrier. vmcnt purity: bias preloaded BEFORE the prologue full drain;
//   the loop body's only VMEM ops are the 8 counted global_load_lds.
// T2: LDS dest linear (global_load_lds requirement); XOR swizzle g^(row&7)
// applied to the GLOBAL source granule and identically on ds_read (rule 21).
template<bool C_F32>
__device__ __forceinline__ void gemm_core(const unsigned short* __restrict__ Ap,
                                          const unsigned short* __restrict__ Bp,
                                          const float* __restrict__ bias,
                                          void* __restrict__ Cp) {
  constexpr int BK = 64, NT = 16;
  const int tid = threadIdx.x;              // 0..511
  const int lane = tid & 63, wave = tid >> 6;
  const int lg = lane >> 4, li = lane & 15;
  const int wr = wave >> 2, wc = wave & 3;  // 2 x 4 wave grid

  // XCD swizzle (nwg = 4*128 = 512, divisible by 8 -> bijective).
  const int orig = blockIdx.y * 4 + blockIdx.x;
  const int wg = (orig & 7) * 64 + (orig >> 3);
  const int bn = wg & 3, bm = wg >> 2;

  const long arow0 = (long)bm * 256;
  const int bcol0 = bn * 256;

  __shared__ __align__(16) unsigned short As[2][256 * BK];  // 64 KB
  __shared__ __align__(16) unsigned short Bs[2][256 * BK];  // 64 KB

  // Bias preload (prologue, drained before the K-loop -> no vmcnt pollution).
  float bv[4];
  #pragma unroll
  for (int n = 0; n < 4; ++n) bv[n] = bias[bcol0 + wc * 64 + n * 16 + li];

  f32x4 acc[8][4];
  #pragma unroll
  for (int m = 0; m < 8; ++m)
    #pragma unroll
    for (int n = 0; n < 4; ++n) acc[m][n] = (f32x4){0.f, 0.f, 0.f, 0.f};

  // Stage K-tile t: 256 rows x 64 bf16 = 2048 16B slots per operand;
  // 512 threads x 4 iters; 8 gload16 per thread total (4 A + 4 B).
  auto stage = [&](int t) {
    const int k0 = t * BK;
    unsigned short* Asb = As[t & 1];
    unsigned short* Bsb = Bs[t & 1];
    #pragma unroll
    for (int it = 0; it < 4; ++it) {
      int s = it * 512 + tid;
      int row = s >> 3;
      int eg = ((s & 7) ^ (row & 7)) * 8;   // pre-swizzled source granule
      gload16(Ap + (arow0 + row) * 1024 + k0 + eg, (unsigned char*)Asb + s * 16);
      gload16(Bp + (long)(bcol0 + row) * 1024 + k0 + eg, (unsigned char*)Bsb + s * 16);
    }
  };

  stage(0);
  stage(1);
  __syncthreads();                          // full drain: tiles 0 and 1 resident

  for (int t = 0; t < NT; ++t) {
    const unsigned short* Asb = As[t & 1];
    const unsigned short* Bsb = Bs[t & 1];

    __builtin_amdgcn_s_setprio(1);
    #pragma unroll
    for (int kk = 0; kk < 2; ++kk) {        // kslice split keeps frag VGPRs ~48
      short8 af[8], bf[4];
      #pragma unroll
      for (int m = 0; m < 8; ++m)
        af[m] = *(const short8*)(Asb + (wr * 128 + m * 16 + li) * BK +
                                 (((kk * 4 + lg) ^ (li & 7)) * 8));
      #pragma unroll
      for (int n = 0; n < 4; ++n)
        bf[n] = *(const short8*)(Bsb + (wc * 64 + n * 16 + li) * BK +
                                 (((kk * 4 + lg) ^ (li & 7)) * 8));
      #pragma unroll
      for (int m = 0; m < 8; ++m)
        #pragma unroll
        for (int n = 0; n < 4; ++n)
          acc[m][n] = __builtin_amdgcn_mfma_f32_16x16x32_bf16(af[m], bf[n], acc[m][n], 0, 0, 0);
    }
    __builtin_amdgcn_s_setprio(0);

    __builtin_amdgcn_s_barrier();           // all waves consumed buf[t&1]
    __builtin_amdgcn_sched_barrier(0);
    if (t + 2 < NT) {
      stage(t + 2);                         // into buf[t&1]; lands after here
      asm volatile("s_waitcnt vmcnt(8)" ::: "memory");   // tile t+1 fully landed
    } else {
      asm volatile("s_waitcnt vmcnt(0)" ::: "memory");
    }
    __builtin_amdgcn_sched_barrier(0);
    __builtin_amdgcn_s_barrier();           // all waves see tile t+1 resident
    __builtin_amdgcn_sched_barrier(0);
  }

  // ---- epilogue: C/D layout col=lane&15, row=(lane>>4)*4+reg ----
  #pragma unroll
  for (int n = 0; n < 4; ++n) {
    int col = bcol0 + wc * 64 + n * 16 + li;
    #pragma unroll
    for (int m = 0; m < 8; ++m) {
      long row = arow0 + wr * 128 + m * 16 + lg * 4;
      #pragma unroll
      for (int r = 0; r < 4; ++r) {
        float v = acc[m][n][r] + bv[n];
        if constexpr (C_F32) ((float*)Cp)[(row + r) * 1024 + col] = v;
        else ((unsigned short*)Cp)[(row + r) * 1024 + col] = f2bf(v);
      }
    }
  }
}

// Three projections batched via blockIdx.z (q,k,v are DIFFERENT A matrices).
__global__ __launch_bounds__(512, 2)
void gemm_proj(const unsigned short* __restrict__ A0, const unsigned short* __restrict__ A1,
               const unsigned short* __restrict__ A2,
               const unsigned short* __restrict__ B0, const unsigned short* __restrict__ B1,
               const unsigned short* __restrict__ B2,
               const float* __restrict__ b0, const float* __restrict__ b1,
               const float* __restrict__ b2,
               unsigned short* __restrict__ C0, unsigned short* __restrict__ C1,
               unsigned short* __restrict__ C2) {
  const int z = blockIdx.z;
  const unsigned short* Ap = z == 0 ? A0 : z == 1 ? A1 : A2;
  const unsigned short* Bp = z == 0 ? B0 : z == 1 ? B1 : B2;
  const float* bias        = z == 0 ? b0 : z == 1 ? b1 : b2;
  unsigned short* Cp       = z == 0 ? C0 : z == 1 ? C1 : C2;
  gemm_core<false>(Ap, Bp, bias, Cp);
}

__global__ __launch_bounds__(512, 2)
void gemm_out(const unsigned short* __restrict__ Ap, const unsigned short* __restrict__ Bp,
              const float* __restrict__ bias, float* __restrict__ Cp) {
  gemm_core<true>(Ap, Bp, bias, Cp);
}

// ---------------- block-local attention per (b,h,c) ----------------
__global__ __launch_bounds__(256)
void attn_kernel(const unsigned short* __restrict__ Qp, const unsigned short* __restrict__ Kp,
                 const unsigned short* __restrict__ Vp, unsigned short* __restrict__ Cc) {
  const int bid = blockIdx.x;
  const int c = bid & 63, h = (bid >> 6) & 15, b = bid >> 10;
  const int tid = threadIdx.x;
  const int lane = tid & 63, wave = tid >> 6;
  const int lg = lane >> 4, li = lane & 15;

  __shared__ __align__(16) unsigned short Qs[128 * 64];
  __shared__ __align__(16) unsigned short Ks[128 * 64];
  __shared__ __align__(16) unsigned short Vs[128 * 64];
  __shared__ __align__(16) unsigned short Ps[4][32 * 128];

  const long base = ((long)(b * 8192 + c * 128)) * 1024 + h * 64;
  #pragma unroll
  for (int it = 0; it < 4; ++it) {
    int slot = it * 256 + tid;
    int row = slot >> 3, col = (slot & 7) * 8;
    long g = base + (long)row * 1024 + col;
    gload16(Qp + g, (unsigned char*)Qs + slot * 16);
    gload16(Kp + g, (unsigned char*)Ks + slot * 16);
    gload16(Vp + g, (unsigned char*)Vs + slot * 16);
  }
  __syncthreads();

  // ---- scores: wave w computes rows [w*32, w*32+32) x all 128 key cols ----
  f32x4 sc[2][8];
  #pragma unroll
  for (int m = 0; m < 2; ++m)
    #pragma unroll
    for (int n = 0; n < 8; ++n) sc[m][n] = (f32x4){0.f, 0.f, 0.f, 0.f};

  short8 qf[2][2];
  #pragma unroll
  for (int m = 0; m < 2; ++m)
    #pragma unroll
    for (int ks = 0; ks < 2; ++ks)
      qf[m][ks] = *(const short8*)(Qs + (wave * 32 + m * 16 + li) * 64 + ks * 32 + lg * 8);

  #pragma unroll
  for (int n = 0; n < 8; ++n) {
    short8 kf0 = *(const short8*)(Ks + (n * 16 + li) * 64 + lg * 8);
    short8 kf1 = *(const short8*)(Ks + (n * 16 + li) * 64 + 32 + lg * 8);
    #pragma unroll
    for (int m = 0; m < 2; ++m) {
      sc[m][n] = __builtin_amdgcn_mfma_f32_16x16x32_bf16(qf[m][0], kf0, sc[m][n], 0, 0, 0);
      sc[m][n] = __builtin_amdgcn_mfma_f32_16x16x32_bf16(qf[m][1], kf1, sc[m][n], 0, 0, 0);
    }
  }

  // ---- softmax: row = m*16 + lg*4 + r lives in 16 lanes (same lg) ----
  #pragma unroll
  for (int m = 0; m < 2; ++m)
    #pragma unroll
    for (int r = 0; r < 4; ++r) {
      float mx = sc[m][0][r];
      #pragma unroll
      for (int n = 1; n < 8; ++n) mx = fmaxf(mx, sc[m][n][r]);
      #pragma unroll
      for (int d = 1; d < 16; d <<= 1) mx = fmaxf(mx, __shfl_xor(mx, d));
      float sum = 0.f;
      #pragma unroll
      for (int n = 0; n < 8; ++n) {
        float p = __expf((sc[m][n][r] - mx) * 0.125f);  // scale 1/sqrt(64)
        sc[m][n][r] = p;
        sum += p;
      }
      #pragma unroll
      for (int d = 1; d < 16; d <<= 1) sum += __shfl_xor(sum, d);
      float rinv = 1.f / sum;
      #pragma unroll
      for (int n = 0; n < 8; ++n) sc[m][n][r] *= rinv;
    }

  // ---- P -> LDS (bf16) ----
  #pragma unroll
  for (int m = 0; m < 2; ++m)
    #pragma unroll
    for (int n = 0; n < 8; ++n)
      #pragma unroll
      for (int r = 0; r < 4; ++r)
        Ps[wave][(m * 16 + lg * 4 + r) * 128 + n * 16 + li] = f2bf(sc[m][n][r]);
  __syncthreads();

  // ---- O = P @ V : [32,128] x [128,64] ----
  f32x4 oc[2][4];
  #pragma unroll
  for (int m = 0; m < 2; ++m)
    #pragma unroll
    for (int n = 0; n < 4; ++n) oc[m][n] = (f32x4){0.f, 0.f, 0.f, 0.f};

  #pragma unroll
  for (int ks = 0; ks < 4; ++ks) {
    short8 vf[4];
    #pragma unroll
    for (int n = 0; n < 4; ++n)
      #pragma unroll
      for (int j = 0; j < 8; ++j)
        vf[n][j] = (short)Vs[(ks * 32 + lg * 8 + j) * 64 + n * 16 + li];
    #pragma unroll
    for (int m = 0; m < 2; ++m) {
      short8 pf = *(const short8*)(Ps[wave] + (m * 16 + li) * 128 + ks * 32 + lg * 8);
      #pragma unroll
      for (int n = 0; n < 4; ++n)
        oc[m][n] = __builtin_amdgcn_mfma_f32_16x16x32_bf16(pf, vf[n], oc[m][n], 0, 0, 0);
    }
  }

  // ---- torch-faithful scrambled concat write ----
  #pragma unroll
  for (int m = 0; m < 2; ++m)
    #pragma unroll
    for (int n = 0; n < 4; ++n)
      #pragma unroll
      for (int r = 0; r < 4; ++r) {
        int p = wave * 32 + m * 16 + lg * 4 + r;
        int d = n * 16 + li;
        int s = c * 128 + h * 8 + (p >> 4);
        int colo = (p & 15) * 64 + d;
        Cc[((long)(b * 8192 + s)) * 1024 + colo] = f2bf(oc[m][n][r]);
      }
}

extern "C" void kernel_launch(void* const* d_in, const int* in_sizes, int n_in,
                              void* d_out, int out_size, void* d_ws, size_t ws_size,
                              hipStream_t stream) {
  (void)in_sizes; (void)n_in; (void)out_size; (void)ws_size;
  const float* q  = (const float*)d_in[0];
  const float* k  = (const float*)d_in[1];
  const float* v  = (const float*)d_in[2];
  const float* WQ = (const float*)d_in[3];
  const float* bQ = (const float*)d_in[4];
  const float* WK = (const float*)d_in[5];
  const float* bK = (const float*)d_in[6];
  const float* WV = (const float*)d_in[7];
  const float* bV = (const float*)d_in[8];
  const float* WO = (const float*)d_in[9];
  const float* bO = (const float*)d_in[10];

  // ws layout: qb | kb | vb | Qp | Kp | Vp | Cc (each 64MB bf16) + weights
  const size_t MN = 32768ull * 1024ull;
  unsigned short* qb  = (unsigned short*)d_ws;
  unsigned short* kb  = qb + MN;
  unsigned short* vb  = kb + MN;
  unsigned short* Qp  = vb + MN;
  unsigned short* Kp  = Qp + MN;
  unsigned short* Vp  = Kp + MN;
  unsigned short* Cc  = Vp + MN;
  unsigned short* WQb = Cc + MN;
  unsigned short* WKb = WQb + (1 << 20);
  unsigned short* WVb = WKb + (1 << 20);
  unsigned short* WOb = WVb + (1 << 20);

  dim3 gw(1024, 1, 4);
  f2b4_kernel<<<gw, 256, 0, stream>>>(WQ, WK, WV, WO, WQb, WKb, WVb, WOb, 1 << 20);

  const int NA = (int)MN;
  dim3 gc(1024, 1, 3);
  cvt3_kernel<<<gc, 256, 0, stream>>>(q, k, v, qb, kb, vb, NA);

  dim3 gp(4, 128, 3);   // 3 projections batched; 512 blocks per z-slice
  gemm_proj<<<gp, 512, 0, stream>>>(qb, kb, vb, WQb, WKb, WVb, bQ, bK, bV, Qp, Kp, Vp);

  attn_kernel<<<4096, 256, 0, stream>>>(Qp, Kp, Vp, Cc);

  dim3 go(4, 128);
  gemm_out<<<go, 512, 0, stream>>>(Cc, WOb, bO, (float*)d_out);
}

// Round 6
// 560.729 us; speedup vs baseline: 1.4070x; 1.0949x over previous
//
#include <hip/hip_runtime.h>
#include <hip/hip_bf16.h>

// Shapes (fixed): B=4, S=8192, D_MODEL=1024, NHEAD=16, D_K=64, D_CHUNK=128,
// C=64 chunks. M = B*S = 32768 rows for all GEMMs, K=N=1024.

typedef __attribute__((ext_vector_type(8))) short short8;   // 8 bf16 (MFMA A/B frag)
typedef __attribute__((ext_vector_type(4))) float f32x4;    // MFMA C/D frag
typedef __attribute__((ext_vector_type(4))) unsigned short us4;

__device__ __forceinline__ unsigned short f2bf(float f) {
  unsigned u = __float_as_uint(f);
  u += 0x7fffu + ((u >> 16) & 1u);          // RNE round to bf16
  return (unsigned short)(u >> 16);
}

__device__ __forceinline__ void gload16(const void* g, void* l) {
  __builtin_amdgcn_global_load_lds((const __attribute__((address_space(1))) void*)g,
                                   (__attribute__((address_space(3))) void*)l, 16, 0, 0);
}

// ---------------- fp32 -> bf16 (4 weight matrices, one dispatch) ----------------
__global__ void f2b4_kernel(const float* __restrict__ i0, const float* __restrict__ i1,
                            const float* __restrict__ i2, const float* __restrict__ i3,
                            unsigned short* __restrict__ o0, unsigned short* __restrict__ o1,
                            unsigned short* __restrict__ o2, unsigned short* __restrict__ o3,
                            int n) {
  const int z = blockIdx.z;
  const float* in = z == 0 ? i0 : z == 1 ? i1 : z == 2 ? i2 : i3;
  unsigned short* out = z == 0 ? o0 : z == 1 ? o1 : z == 2 ? o2 : o3;
  int i = (blockIdx.x * 256 + threadIdx.x) * 4;
  if (i >= n) return;
  f32x4 x = *(const f32x4*)(in + i);
  us4 o;
  #pragma unroll
  for (int j = 0; j < 4; ++j) o[j] = f2bf(x[j]);
  *(us4*)(out + i) = o;
}

// ---------------- fp32 -> bf16 (q,k,v activations in one dispatch) ----------------
__global__ __launch_bounds__(256)
void cvt3_kernel(const float* __restrict__ i0, const float* __restrict__ i1,
                 const float* __restrict__ i2, unsigned short* __restrict__ o0,
                 unsigned short* __restrict__ o1, unsigned short* __restrict__ o2, int n) {
  const int z = blockIdx.z;
  const float* in = z == 0 ? i0 : z == 1 ? i1 : i2;
  unsigned short* out = z == 0 ? o0 : z == 1 ? o1 : o2;
  int stride = gridDim.x * 256 * 8;
  for (int i = (blockIdx.x * 256 + threadIdx.x) * 8; i < n; i += stride) {
    f32x4 a = *(const f32x4*)(in + i);
    f32x4 b = *(const f32x4*)(in + i + 4);
    short8 o;
    #pragma unroll
    for (int j = 0; j < 4; ++j) {
      o[j]     = (short)f2bf(a[j]);
      o[4 + j] = (short)f2bf(b[j]);
    }
    *(short8*)(out + i) = o;
  }
}

// ---------------- GEMM core: C[M,1024] = A[M,1024](bf16) * B[1024,1024]^T + bias ----
// 256x256 tile, BK=64, 512 threads = 8 waves (2M x 4N), per-wave output 128x64.
//
// 8-phase schedule (m201 skeleton). Per K-tile t, 4 phases x {ds_read subtile;
// stage 1 half-tile (2 gload_lds); s_barrier; setprio(1); 16 MFMA; setprio(0);
// s_barrier}. Reads per phase: 8/8/4/4.
//   P0: a[m0-3][kk0] + b[n0-3][kk0] -> MFMA (m0-3, n, kk0); stage A-lo(t+1)
//   P1: a[m0-3][kk1] + b[n0-3][kk1] -> MFMA (m0-3, n, kk1); stage A-hi(t+1)
//   P2: a[m4-7][kk0]               -> MFMA (m4-7, n, kk0); stage B-lo(t+2)
//   P3: a[m4-7][kk1]               -> MFMA (m4-7, n, kk1); stage B-hi(t+2); vmcnt(4)
// Hazard discipline (WAR-free by construction): a wave's reads complete before
// its in-phase MFMA (compiler lgkm waits on the data dep), hence before that
// phase's closing barrier; a slot is staged only in phases strictly after the
// slot's last-reader phase's closing barrier. B-slots of buffer pi are read
// only in P0/P1 of tile t -> staged for t+2 at t.P2/P3. A-slots are read
// through P3 -> staged for t+1 at t.P0/P1 (buffer pi^1, last read by t-1).
// Counted vmcnt(4) once per tile: drains A(t+1) (issued >=2 phases earlier),
// leaves B(t+2)'s 4 loads in flight across the tile boundary. vmcnt purity:
// bias preloaded before the prologue drain; no other VMEM in the loop body.
// T2: LDS dest linear (global_load_lds requirement); XOR swizzle g^(row&7)
// applied to the GLOBAL source granule and identically on ds_read (rule 21).
// Epilogue: wave-private LDS bounce (stride 68 floats, 2-way-free banks) so
// C stores are 128-256B contiguous per 16-lane group (kills the 1.7x HBM
// write amplification of direct MFMA-layout 32B-fragment stores).
template<bool C_F32>
__device__ __forceinline__ void gemm_core(const unsigned short* __restrict__ Ap,
                                          const unsigned short* __restrict__ Bp,
                                          const float* __restrict__ bias,
                                          void* __restrict__ Cp) {
  constexpr int BK = 64, NT = 16;
  const int tid = threadIdx.x;              // 0..511
  const int lane = tid & 63, wave = tid >> 6;
  const int lg = lane >> 4, li = lane & 15;
  const int wr = wave >> 2, wc = wave & 3;  // 2 x 4 wave grid

  // XCD swizzle (nwg = 512, divisible by 8 -> bijective).
  const int orig = blockIdx.y * 4 + blockIdx.x;
  const int wg = (orig & 7) * 64 + (orig >> 3);
  const int bn = wg & 3, bm = wg >> 2;

  const long arow0 = (long)bm * 256;
  const int bcol0 = bn * 256;

  __shared__ __align__(16) unsigned short As[2][256 * BK];  // 64 KB
  __shared__ __align__(16) unsigned short Bs[2][256 * BK];  // 64 KB

  // Bias preload (drained before the K-loop -> no vmcnt pollution).
  float bv[4];
  #pragma unroll
  for (int n = 0; n < 4; ++n) bv[n] = bias[bcol0 + wc * 64 + n * 16 + li];

  f32x4 acc[8][4];
  #pragma unroll
  for (int m = 0; m < 8; ++m)
    #pragma unroll
    for (int n = 0; n < 4; ++n) acc[m][n] = (f32x4){0.f, 0.f, 0.f, 0.f};

  // Stage one half-tile: h = 0:A-lo 1:A-hi 2:B-lo 3:B-hi of tile u.
  // 128 rows x 64 bf16 = 1024 x 16B slots; 2 gload16 per thread.
  auto stage_half = [&](int u, int h) {
    const int k0 = u * BK;
    const int half = h & 1;
    unsigned short* dst = (h < 2 ? As[u & 1] : Bs[u & 1]) + half * (128 * BK);
    const unsigned short* src = (h < 2) ? Ap : Bp;
    const long rbase = (h < 2) ? (arow0 + half * 128) : (long)(bcol0 + half * 128);
    #pragma unroll
    for (int it = 0; it < 2; ++it) {
      int s = it * 512 + tid;              // 0..1023
      int row = s >> 3;                    // row within half; row&7 == global row&7
      int eg = ((s & 7) ^ (row & 7)) * 8;  // pre-swizzled source granule
      gload16(src + (rbase + row) * 1024 + k0 + eg, (unsigned char*)dst + s * 16);
    }
  };

  // Prologue: A(0), B(0) resident; B(1) in flight.
  stage_half(0, 0); stage_half(0, 1); stage_half(0, 2); stage_half(0, 3);
  stage_half(1, 2); stage_half(1, 3);
  asm volatile("s_waitcnt vmcnt(4)" ::: "memory");   // A(0)+B(0) landed
  __builtin_amdgcn_sched_barrier(0);
  __builtin_amdgcn_s_barrier();

  for (int t = 0; t < NT; ++t) {
    const unsigned short* Asb = As[t & 1];
    const unsigned short* Bsb = Bs[t & 1];

    auto LDA = [&](int m, int kk) {
      return *(const short8*)(Asb + (wr * 128 + m * 16 + li) * BK +
                              (((kk * 4 + lg) ^ (li & 7)) * 8));
    };
    auto LDB = [&](int n, int kk) {
      return *(const short8*)(Bsb + (wc * 64 + n * 16 + li) * BK +
                              (((kk * 4 + lg) ^ (li & 7)) * 8));
    };

    short8 b0[4], b1[4];

    // ---- P0 ----
    {
      short8 a0[4];
      #pragma unroll
      for (int i = 0; i < 4; ++i) a0[i] = LDA(i, 0);
      #pragma unroll
      for (int n = 0; n < 4; ++n) b0[n] = LDB(n, 0);
      if (t + 1 < NT) stage_half(t + 1, 0);
      __builtin_amdgcn_s_barrier();
      __builtin_amdgcn_s_setprio(1);
      #pragma unroll
      for (int i = 0; i < 4; ++i)
        #pragma unroll
        for (int n = 0; n < 4; ++n)
          acc[i][n] = __builtin_amdgcn_mfma_f32_16x16x32_bf16(a0[i], b0[n], acc[i][n], 0, 0, 0);
      __builtin_amdgcn_s_setprio(0);
      __builtin_amdgcn_s_barrier();
    }
    // ---- P1 ----
    {
      short8 a1[4];
      #pragma unroll
      for (int i = 0; i < 4; ++i) a1[i] = LDA(i, 1);
      #pragma unroll
      for (int n = 0; n < 4; ++n) b1[n] = LDB(n, 1);
      if (t + 1 < NT) stage_half(t + 1, 1);
      __builtin_amdgcn_s_barrier();
      __builtin_amdgcn_s_setprio(1);
      #pragma unroll
      for (int i = 0; i < 4; ++i)
        #pragma unroll
        for (int n = 0; n < 4; ++n)
          acc[i][n] = __builtin_amdgcn_mfma_f32_16x16x32_bf16(a1[i], b1[n], acc[i][n], 0, 0, 0);
      __builtin_amdgcn_s_setprio(0);
      __builtin_amdgcn_s_barrier();
    }
    // ---- P2 ----
    {
      short8 a2[4];
      #pragma unroll
      for (int i = 0; i < 4; ++i) a2[i] = LDA(4 + i, 0);
      if (t + 2 < NT) stage_half(t + 2, 2);
      __builtin_amdgcn_s_barrier();
      __builtin_amdgcn_s_setprio(1);
      #pragma unroll
      for (int i = 0; i < 4; ++i)
        #pragma unroll
        for (int n = 0; n < 4; ++n)
          acc[4 + i][n] = __builtin_amdgcn_mfma_f32_16x16x32_bf16(a2[i], b0[n], acc[4 + i][n], 0, 0, 0);
      __builtin_amdgcn_s_setprio(0);
      __builtin_amdgcn_s_barrier();
    }
    // ---- P3 ----
    {
      short8 a3[4];
      #pragma unroll
      for (int i = 0; i < 4; ++i) a3[i] = LDA(4 + i, 1);
      if (t + 2 < NT) stage_half(t + 2, 3);
      if (t + 2 < NT) {
        asm volatile("s_waitcnt vmcnt(4)" ::: "memory");   // A(t+1) fully landed
      } else {
        asm volatile("s_waitcnt vmcnt(0)" ::: "memory");
      }
      __builtin_amdgcn_sched_barrier(0);
      __builtin_amdgcn_s_barrier();                        // rendezvous: tile t+1 ready
      __builtin_amdgcn_s_setprio(1);
      #pragma unroll
      for (int i = 0; i < 4; ++i)
        #pragma unroll
        for (int n = 0; n < 4; ++n)
          acc[4 + i][n] = __builtin_amdgcn_mfma_f32_16x16x32_bf16(a3[i], b1[n], acc[4 + i][n], 0, 0, 0);
      __builtin_amdgcn_s_setprio(0);
      __builtin_amdgcn_s_barrier();
    }
  }

  // ---- epilogue: coalesced C stores via wave-private LDS bounce ----
  // MFMA C/D layout: col=li, row=lg*4+r. Bounce each 16x64 m-group through
  // LDS (stride 68 floats) and store row-contiguous (16 lanes = 64 cols).
  float* wsc = (float*)As + wave * (16 * 68);
  #pragma unroll
  for (int m = 0; m < 8; ++m) {
    #pragma unroll
    for (int n = 0; n < 4; ++n)
      #pragma unroll
      for (int r = 0; r < 4; ++r)
        wsc[(lg * 4 + r) * 68 + n * 16 + li] = acc[m][n][r] + bv[n];
    asm volatile("s_waitcnt lgkmcnt(0)" ::: "memory");
    __builtin_amdgcn_sched_barrier(0);
    #pragma unroll
    for (int i = 0; i < 4; ++i) {
      int slot = i * 64 + lane;
      int r = slot >> 4, g = slot & 15;
      f32x4 vv = *(const f32x4*)(wsc + r * 68 + g * 4);
      long grow = arow0 + wr * 128 + m * 16 + r;
      long gcol = bcol0 + wc * 64 + g * 4;
      if constexpr (C_F32) {
        *(f32x4*)((float*)Cp + grow * 1024 + gcol) = vv;
      } else {
        us4 o;
        #pragma unroll
        for (int j = 0; j < 4; ++j) o[j] = f2bf(vv[j]);
        *(us4*)((unsigned short*)Cp + grow * 1024 + gcol) = o;
      }
    }
    asm volatile("s_waitcnt lgkmcnt(0)" ::: "memory");   // reads done before next overwrite
    __builtin_amdgcn_sched_barrier(0);
  }
}

// Three projections batched via blockIdx.z (q,k,v are DIFFERENT A matrices).
__global__ __launch_bounds__(512, 2)
void gemm_proj(const unsigned short* __restrict__ A0, const unsigned short* __restrict__ A1,
               const unsigned short* __restrict__ A2,
               const unsigned short* __restrict__ B0, const unsigned short* __restrict__ B1,
               const unsigned short* __restrict__ B2,
               const float* __restrict__ b0, const float* __restrict__ b1,
               const float* __restrict__ b2,
               unsigned short* __restrict__ C0, unsigned short* __restrict__ C1,
               unsigned short* __restrict__ C2) {
  const int z = blockIdx.z;
  const unsigned short* Ap = z == 0 ? A0 : z == 1 ? A1 : A2;
  const unsigned short* Bp = z == 0 ? B0 : z == 1 ? B1 : B2;
  const float* bias        = z == 0 ? b0 : z == 1 ? b1 : b2;
  unsigned short* Cp       = z == 0 ? C0 : z == 1 ? C1 : C2;
  gemm_core<false>(Ap, Bp, bias, Cp);
}

__global__ __launch_bounds__(512, 2)
void gemm_out(const unsigned short* __restrict__ Ap, const unsigned short* __restrict__ Bp,
              const float* __restrict__ bias, float* __restrict__ Cp) {
  gemm_core<true>(Ap, Bp, bias, Cp);
}

// ---------------- block-local attention per (b,h,c) ----------------
__global__ __launch_bounds__(256)
void attn_kernel(const unsigned short* __restrict__ Qp, const unsigned short* __restrict__ Kp,
                 const unsigned short* __restrict__ Vp, unsigned short* __restrict__ Cc) {
  const int bid = blockIdx.x;
  const int c = bid & 63, h = (bid >> 6) & 15, b = bid >> 10;
  const int tid = threadIdx.x;
  const int lane = tid & 63, wave = tid >> 6;
  const int lg = lane >> 4, li = lane & 15;

  __shared__ __align__(16) unsigned short Qs[128 * 64];
  __shared__ __align__(16) unsigned short Ks[128 * 64];
  __shared__ __align__(16) unsigned short Vs[128 * 64];
  __shared__ __align__(16) unsigned short Ps[4][32 * 128];

  const long base = ((long)(b * 8192 + c * 128)) * 1024 + h * 64;
  #pragma unroll
  for (int it = 0; it < 4; ++it) {
    int slot = it * 256 + tid;
    int row = slot >> 3, col = (slot & 7) * 8;
    long g = base + (long)row * 1024 + col;
    gload16(Qp + g, (unsigned char*)Qs + slot * 16);
    gload16(Kp + g, (unsigned char*)Ks + slot * 16);
    gload16(Vp + g, (unsigned char*)Vs + slot * 16);
  }
  __syncthreads();

  // ---- scores: wave w computes rows [w*32, w*32+32) x all 128 key cols ----
  f32x4 sc[2][8];
  #pragma unroll
  for (int m = 0; m < 2; ++m)
    #pragma unroll
    for (int n = 0; n < 8; ++n) sc[m][n] = (f32x4){0.f, 0.f, 0.f, 0.f};

  short8 qf[2][2];
  #pragma unroll
  for (int m = 0; m < 2; ++m)
    #pragma unroll
    for (int ks = 0; ks < 2; ++ks)
      qf[m][ks] = *(const short8*)(Qs + (wave * 32 + m * 16 + li) * 64 + ks * 32 + lg * 8);

  #pragma unroll
  for (int n = 0; n < 8; ++n) {
    short8 kf0 = *(const short8*)(Ks + (n * 16 + li) * 64 + lg * 8);
    short8 kf1 = *(const short8*)(Ks + (n * 16 + li) * 64 + 32 + lg * 8);
    #pragma unroll
    for (int m = 0; m < 2; ++m) {
      sc[m][n] = __builtin_amdgcn_mfma_f32_16x16x32_bf16(qf[m][0], kf0, sc[m][n], 0, 0, 0);
      sc[m][n] = __builtin_amdgcn_mfma_f32_16x16x32_bf16(qf[m][1], kf1, sc[m][n], 0, 0, 0);
    }
  }

  // ---- softmax: row = m*16 + lg*4 + r lives in 16 lanes (same lg) ----
  #pragma unroll
  for (int m = 0; m < 2; ++m)
    #pragma unroll
    for (int r = 0; r < 4; ++r) {
      float mx = sc[m][0][r];
      #pragma unroll
      for (int n = 1; n < 8; ++n) mx = fmaxf(mx, sc[m][n][r]);
      #pragma unroll
      for (int d = 1; d < 16; d <<= 1) mx = fmaxf(mx, __shfl_xor(mx, d));
      float sum = 0.f;
      #pragma unroll
      for (int n = 0; n < 8; ++n) {
        float p = __expf((sc[m][n][r] - mx) * 0.125f);  // scale 1/sqrt(64)
        sc[m][n][r] = p;
        sum += p;
      }
      #pragma unroll
      for (int d = 1; d < 16; d <<= 1) sum += __shfl_xor(sum, d);
      float rinv = 1.f / sum;
      #pragma unroll
      for (int n = 0; n < 8; ++n) sc[m][n][r] *= rinv;
    }

  // ---- P -> LDS (bf16) ----
  #pragma unroll
  for (int m = 0; m < 2; ++m)
    #pragma unroll
    for (int n = 0; n < 8; ++n)
      #pragma unroll
      for (int r = 0; r < 4; ++r)
        Ps[wave][(m * 16 + lg * 4 + r) * 128 + n * 16 + li] = f2bf(sc[m][n][r]);
  __syncthreads();

  // ---- O = P @ V : [32,128] x [128,64] ----
  f32x4 oc[2][4];
  #pragma unroll
  for (int m = 0; m < 2; ++m)
    #pragma unroll
    for (int n = 0; n < 4; ++n) oc[m][n] = (f32x4){0.f, 0.f, 0.f, 0.f};

  #pragma unroll
  for (int ks = 0; ks < 4; ++ks) {
    short8 vf[4];
    #pragma unroll
    for (int n = 0; n < 4; ++n)
      #pragma unroll
      for (int j = 0; j < 8; ++j)
        vf[n][j] = (short)Vs[(ks * 32 + lg * 8 + j) * 64 + n * 16 + li];
    #pragma unroll
    for (int m = 0; m < 2; ++m) {
      short8 pf = *(const short8*)(Ps[wave] + (m * 16 + li) * 128 + ks * 32 + lg * 8);
      #pragma unroll
      for (int n = 0; n < 4; ++n)
        oc[m][n] = __builtin_amdgcn_mfma_f32_16x16x32_bf16(pf, vf[n], oc[m][n], 0, 0, 0);
    }
  }

  // ---- torch-faithful scrambled concat write ----
  #pragma unroll
  for (int m = 0; m < 2; ++m)
    #pragma unroll
    for (int n = 0; n < 4; ++n)
      #pragma unroll
      for (int r = 0; r < 4; ++r) {
        int p = wave * 32 + m * 16 + lg * 4 + r;
        int d = n * 16 + li;
        int s = c * 128 + h * 8 + (p >> 4);
        int colo = (p & 15) * 64 + d;
        Cc[((long)(b * 8192 + s)) * 1024 + colo] = f2bf(oc[m][n][r]);
      }
}

extern "C" void kernel_launch(void* const* d_in, const int* in_sizes, int n_in,
                              void* d_out, int out_size, void* d_ws, size_t ws_size,
                              hipStream_t stream) {
  (void)in_sizes; (void)n_in; (void)out_size; (void)ws_size;
  const float* q  = (const float*)d_in[0];
  const float* k  = (const float*)d_in[1];
  const float* v  = (const float*)d_in[2];
  const float* WQ = (const float*)d_in[3];
  const float* bQ = (const float*)d_in[4];
  const float* WK = (const float*)d_in[5];
  const float* bK = (const float*)d_in[6];
  const float* WV = (const float*)d_in[7];
  const float* bV = (const float*)d_in[8];
  const float* WO = (const float*)d_in[9];
  const float* bO = (const float*)d_in[10];

  // ws layout: qb | kb | vb | Qp | Kp | Vp | Cc (each 64MB bf16) + weights
  const size_t MN = 32768ull * 1024ull;
  unsigned short* qb  = (unsigned short*)d_ws;
  unsigned short* kb  = qb + MN;
  unsigned short* vb  = kb + MN;
  unsigned short* Qp  = vb + MN;
  unsigned short* Kp  = Qp + MN;
  unsigned short* Vp  = Kp + MN;
  unsigned short* Cc  = Vp + MN;
  unsigned short* WQb = Cc + MN;
  unsigned short* WKb = WQb + (1 << 20);
  unsigned short* WVb = WKb + (1 << 20);
  unsigned short* WOb = WVb + (1 << 20);

  dim3 gw(1024, 1, 4);
  f2b4_kernel<<<gw, 256, 0, stream>>>(WQ, WK, WV, WO, WQb, WKb, WVb, WOb, 1 << 20);

  const int NA = (int)MN;
  dim3 gc(1024, 1, 3);
  cvt3_kernel<<<gc, 256, 0, stream>>>(q, k, v, qb, kb, vb, NA);

  dim3 gp(4, 128, 3);   // 3 projections batched; 512 blocks per z-slice
  gemm_proj<<<gp, 512, 0, stream>>>(qb, kb, vb, WQb, WKb, WVb, bQ, bK, bV, Qp, Kp, Vp);

  attn_kernel<<<4096, 256, 0, stream>>>(Qp, Kp, Vp, Cc);

  dim3 go(4, 128);
  gemm_out<<<go, 512, 0, stream>>>(Cc, WOb, bO, (float*)d_out);
}

// Round 7
// 559.898 us; speedup vs baseline: 1.4090x; 1.0015x over previous
//
#include <hip/hip_runtime.h>
#include <hip/hip_bf16.h>

// Shapes (fixed): B=4, S=8192, D_MODEL=1024, NHEAD=16, D_K=64, D_CHUNK=128,
// C=64 chunks. M = B*S = 32768 rows for all GEMMs, K=N=1024.

typedef __attribute__((ext_vector_type(8))) short short8;   // 8 bf16 (MFMA A/B frag)
typedef __attribute__((ext_vector_type(4))) float f32x4;    // MFMA C/D frag
typedef __attribute__((ext_vector_type(4))) unsigned short us4;

__device__ __forceinline__ unsigned short f2bf(float f) {
  unsigned u = __float_as_uint(f);
  u += 0x7fffu + ((u >> 16) & 1u);          // RNE round to bf16
  return (unsigned short)(u >> 16);
}

__device__ __forceinline__ void gload16(const void* g, void* l) {
  __builtin_amdgcn_global_load_lds((const __attribute__((address_space(1))) void*)g,
                                   (__attribute__((address_space(3))) void*)l, 16, 0, 0);
}

// ---------------- fp32 -> bf16 (4 weight matrices, one dispatch) ----------------
__global__ void f2b4_kernel(const float* __restrict__ i0, const float* __restrict__ i1,
                            const float* __restrict__ i2, const float* __restrict__ i3,
                            unsigned short* __restrict__ o0, unsigned short* __restrict__ o1,
                            unsigned short* __restrict__ o2, unsigned short* __restrict__ o3,
                            int n) {
  const int z = blockIdx.z;
  const float* in = z == 0 ? i0 : z == 1 ? i1 : z == 2 ? i2 : i3;
  unsigned short* out = z == 0 ? o0 : z == 1 ? o1 : z == 2 ? o2 : o3;
  int i = (blockIdx.x * 256 + threadIdx.x) * 4;
  if (i >= n) return;
  f32x4 x = *(const f32x4*)(in + i);
  us4 o;
  #pragma unroll
  for (int j = 0; j < 4; ++j) o[j] = f2bf(x[j]);
  *(us4*)(out + i) = o;
}

// ---------------- GEMM core: C[M,1024] = A[M,1024] * B[1024,1024]^T + bias ----
// 256x256 tile, BK=64, 512 threads = 8 waves (2M x 4N), per-wave output 128x64.
// 8-phase schedule (m201 skeleton), per K-tile t: 4 phases x {ds_read subtile;
// stage; s_barrier; setprio(1); 16 MFMA; setprio(0); s_barrier}.
//
// A_F32=false (proven round-6 path, byte-identical): A staged via
// global_load_lds at P0/P1; B(t+2) at P2/P3; counted vmcnt(4) at P3 drains
// A(t+1), leaves B(t+2) in flight.
//
// A_F32=true (fused fp32->bf16): A(t+1) fp32 loaded to REGISTERS at P0
// (8 dwordx4/thread), converted + ds_write_b128 to the SAME linear swizzled
// slots at P2, then lgkmcnt(0)+sched_barrier publishes before P2's
// mid-barrier; consumers read from t+1.P0 (after t.P3's closing barrier).
// The data-dep register wait at P2's cvt drains all OLDER VMEM (FIFO),
// including B(t+1) -> B(t+1) is resident in every wave before P2's
// mid-barrier, hence for all waves at t+1.P0. B(t+2)'s loads (issued after
// the A loads) stay in flight across the tile boundary. No manual vmcnt
// needed in the A_F32 loop. WAR: As[(t+1)&1] last read by t-1's P2/P3
// (before t-1.P3's closing barrier) -> write at t.P2 is safe.
// T2: LDS dest linear; XOR swizzle applied to the GLOBAL source granule and
// identically on ds_read (rule 21). vmcnt purity: bias preloaded up front.
// Epilogue: coalesced C stores via wave-private LDS bounce (stride 68 f32).
template<bool A_F32, bool C_F32>
__device__ __forceinline__ void gemm_core(const void* __restrict__ Apv,
                                          const unsigned short* __restrict__ Bp,
                                          const float* __restrict__ bias,
                                          void* __restrict__ Cp) {
  constexpr int BK = 64, NT = 16;
  const int tid = threadIdx.x;              // 0..511
  const int lane = tid & 63, wave = tid >> 6;
  const int lg = lane >> 4, li = lane & 15;
  const int wr = wave >> 2, wc = wave & 3;  // 2 x 4 wave grid

  const unsigned short* Ab = (const unsigned short*)Apv;  // bf16 path
  const float* Af = (const float*)Apv;                    // fp32 path

  // XCD swizzle (nwg = 512, divisible by 8 -> bijective).
  const int orig = blockIdx.y * 4 + blockIdx.x;
  const int wg = (orig & 7) * 64 + (orig >> 3);
  const int bn = wg & 3, bm = wg >> 2;

  const long arow0 = (long)bm * 256;
  const int bcol0 = bn * 256;

  __shared__ __align__(16) unsigned short As[2][256 * BK];  // 64 KB
  __shared__ __align__(16) unsigned short Bs[2][256 * BK];  // 64 KB

  // Bias preload (drained before the K-loop -> no vmcnt pollution).
  float bv[4];
  #pragma unroll
  for (int n = 0; n < 4; ++n) bv[n] = bias[bcol0 + wc * 64 + n * 16 + li];

  f32x4 acc[8][4];
  #pragma unroll
  for (int m = 0; m < 8; ++m)
    #pragma unroll
    for (int n = 0; n < 4; ++n) acc[m][n] = (f32x4){0.f, 0.f, 0.f, 0.f};

  // Stage one half-tile via global_load_lds: h = 0:A-lo 1:A-hi 2:B-lo 3:B-hi.
  auto stage_half = [&](int u, int h) {
    const int k0 = u * BK;
    const int half = h & 1;
    unsigned short* dst = (h < 2 ? As[u & 1] : Bs[u & 1]) + half * (128 * BK);
    const unsigned short* src = (h < 2) ? Ab : Bp;
    const long rbase = (h < 2) ? (arow0 + half * 128) : (long)(bcol0 + half * 128);
    #pragma unroll
    for (int it = 0; it < 2; ++it) {
      int s = it * 512 + tid;              // 0..1023
      int row = s >> 3;
      int eg = ((s & 7) ^ (row & 7)) * 8;  // pre-swizzled source granule
      gload16(src + (rbase + row) * 1024 + k0 + eg, (unsigned char*)dst + s * 16);
    }
  };

  // fp32-A register staging (A_F32 path). 4 slots/thread (2 halves x 2).
  f32x4 areg[4][2];
  auto issueA = [&](int u) {
    #pragma unroll
    for (int hf = 0; hf < 2; ++hf)
      #pragma unroll
      for (int it = 0; it < 2; ++it) {
        int s = it * 512 + tid;
        int row = s >> 3;
        int ce = ((s & 7) ^ (row & 7)) * 8;
        const float* p = Af + (arow0 + hf * 128 + row) * 1024 + u * BK + ce;
        areg[hf * 2 + it][0] = *(const f32x4*)p;
        areg[hf * 2 + it][1] = *(const f32x4*)(p + 4);
      }
  };
  auto writeA = [&](int u) {
    unsigned short* dstb = As[u & 1];
    #pragma unroll
    for (int hf = 0; hf < 2; ++hf)
      #pragma unroll
      for (int it = 0; it < 2; ++it) {
        int s = it * 512 + tid;
        short8 o;
        #pragma unroll
        for (int j = 0; j < 4; ++j) {
          o[j]     = (short)f2bf(areg[hf * 2 + it][0][j]);
          o[4 + j] = (short)f2bf(areg[hf * 2 + it][1][j]);
        }
        *(short8*)((unsigned char*)(dstb + hf * (128 * BK)) + s * 16) = o;
      }
    asm volatile("s_waitcnt lgkmcnt(0)" ::: "memory");   // publish ds_writes
    __builtin_amdgcn_sched_barrier(0);
  };

  // ---- prologue ----
  if constexpr (A_F32) {
    stage_half(0, 2); stage_half(0, 3);   // B(0)
    issueA(0);                            // A(0) -> regs
    stage_half(1, 2); stage_half(1, 3);   // B(1), stays in flight
    writeA(0);                            // data-dep vmcnt drains B(0)+A(0)
    __builtin_amdgcn_s_barrier();
  } else {
    stage_half(0, 0); stage_half(0, 1); stage_half(0, 2); stage_half(0, 3);
    stage_half(1, 2); stage_half(1, 3);
    asm volatile("s_waitcnt vmcnt(4)" ::: "memory");   // A(0)+B(0) landed
    __builtin_amdgcn_sched_barrier(0);
    __builtin_amdgcn_s_barrier();
  }

  for (int t = 0; t < NT; ++t) {
    const unsigned short* Asb = As[t & 1];
    const unsigned short* Bsb = Bs[t & 1];

    auto LDA = [&](int m, int kk) {
      return *(const short8*)(Asb + (wr * 128 + m * 16 + li) * BK +
                              (((kk * 4 + lg) ^ (li & 7)) * 8));
    };
    auto LDB = [&](int n, int kk) {
      return *(const short8*)(Bsb + (wc * 64 + n * 16 + li) * BK +
                              (((kk * 4 + lg) ^ (li & 7)) * 8));
    };

    short8 b0[4], b1[4];

    // ---- P0 ----
    {
      short8 a0[4];
      #pragma unroll
      for (int i = 0; i < 4; ++i) a0[i] = LDA(i, 0);
      #pragma unroll
      for (int n = 0; n < 4; ++n) b0[n] = LDB(n, 0);
      if constexpr (A_F32) {
        if (t + 1 < NT) issueA(t + 1);
      } else {
        if (t + 1 < NT) stage_half(t + 1, 0);
      }
      __builtin_amdgcn_s_barrier();
      __builtin_amdgcn_s_setprio(1);
      #pragma unroll
      for (int i = 0; i < 4; ++i)
        #pragma unroll
        for (int n = 0; n < 4; ++n)
          acc[i][n] = __builtin_amdgcn_mfma_f32_16x16x32_bf16(a0[i], b0[n], acc[i][n], 0, 0, 0);
      __builtin_amdgcn_s_setprio(0);
      __builtin_amdgcn_s_barrier();
    }
    // ---- P1 ----
    {
      short8 a1[4];
      #pragma unroll
      for (int i = 0; i < 4; ++i) a1[i] = LDA(i, 1);
      #pragma unroll
      for (int n = 0; n < 4; ++n) b1[n] = LDB(n, 1);
      if constexpr (!A_F32) {
        if (t + 1 < NT) stage_half(t + 1, 1);
      }
      __builtin_amdgcn_s_barrier();
      __builtin_amdgcn_s_setprio(1);
      #pragma unroll
      for (int i = 0; i < 4; ++i)
        #pragma unroll
        for (int n = 0; n < 4; ++n)
          acc[i][n] = __builtin_amdgcn_mfma_f32_16x16x32_bf16(a1[i], b1[n], acc[i][n], 0, 0, 0);
      __builtin_amdgcn_s_setprio(0);
      __builtin_amdgcn_s_barrier();
    }
    // ---- P2 ----
    {
      short8 a2[4];
      #pragma unroll
      for (int i = 0; i < 4; ++i) a2[i] = LDA(4 + i, 0);
      if (t + 2 < NT) stage_half(t + 2, 2);
      if constexpr (A_F32) {
        if (t + 1 < NT) writeA(t + 1);   // cvt+ds_write+lgkm0; drains B(t+1)
      }
      __builtin_amdgcn_s_barrier();
      __builtin_amdgcn_s_setprio(1);
      #pragma unroll
      for (int i = 0; i < 4; ++i)
        #pragma unroll
        for (int n = 0; n < 4; ++n)
          acc[4 + i][n] = __builtin_amdgcn_mfma_f32_16x16x32_bf16(a2[i], b0[n], acc[4 + i][n], 0, 0, 0);
      __builtin_amdgcn_s_setprio(0);
      __builtin_amdgcn_s_barrier();
    }
    // ---- P3 ----
    {
      short8 a3[4];
      #pragma unroll
      for (int i = 0; i < 4; ++i) a3[i] = LDA(4 + i, 1);
      if (t + 2 < NT) stage_half(t + 2, 3);
      if constexpr (!A_F32) {
        if (t + 2 < NT) {
          asm volatile("s_waitcnt vmcnt(4)" ::: "memory");   // A(t+1) landed
        } else {
          asm volatile("s_waitcnt vmcnt(0)" ::: "memory");
        }
        __builtin_amdgcn_sched_barrier(0);
      }
      __builtin_amdgcn_s_barrier();                          // tile t+1 ready
      __builtin_amdgcn_s_setprio(1);
      #pragma unroll
      for (int i = 0; i < 4; ++i)
        #pragma unroll
        for (int n = 0; n < 4; ++n)
          acc[4 + i][n] = __builtin_amdgcn_mfma_f32_16x16x32_bf16(a3[i], b1[n], acc[4 + i][n], 0, 0, 0);
      __builtin_amdgcn_s_setprio(0);
      __builtin_amdgcn_s_barrier();
    }
  }

  // ---- epilogue: coalesced C stores via wave-private LDS bounce ----
  float* wsc = (float*)As + wave * (16 * 68);
  #pragma unroll
  for (int m = 0; m < 8; ++m) {
    #pragma unroll
    for (int n = 0; n < 4; ++n)
      #pragma unroll
      for (int r = 0; r < 4; ++r)
        wsc[(lg * 4 + r) * 68 + n * 16 + li] = acc[m][n][r] + bv[n];
    asm volatile("s_waitcnt lgkmcnt(0)" ::: "memory");
    __builtin_amdgcn_sched_barrier(0);
    #pragma unroll
    for (int i = 0; i < 4; ++i) {
      int slot = i * 64 + lane;
      int r = slot >> 4, g = slot & 15;
      f32x4 vv = *(const f32x4*)(wsc + r * 68 + g * 4);
      long grow = arow0 + wr * 128 + m * 16 + r;
      long gcol = bcol0 + wc * 64 + g * 4;
      if constexpr (C_F32) {
        *(f32x4*)((float*)Cp + grow * 1024 + gcol) = vv;
      } else {
        us4 o;
        #pragma unroll
        for (int j = 0; j < 4; ++j) o[j] = f2bf(vv[j]);
        *(us4*)((unsigned short*)Cp + grow * 1024 + gcol) = o;
      }
    }
    asm volatile("s_waitcnt lgkmcnt(0)" ::: "memory");   // reads done before overwrite
    __builtin_amdgcn_sched_barrier(0);
  }
}

// Three projections batched via blockIdx.z; A operands are the RAW fp32
// q,k,v inputs (conversion fused into staging).
__global__ __launch_bounds__(512, 2)
void gemm_proj(const float* __restrict__ A0, const float* __restrict__ A1,
               const float* __restrict__ A2,
               const unsigned short* __restrict__ B0, const unsigned short* __restrict__ B1,
               const unsigned short* __restrict__ B2,
               const float* __restrict__ b0, const float* __restrict__ b1,
               const float* __restrict__ b2,
               unsigned short* __restrict__ C0, unsigned short* __restrict__ C1,
               unsigned short* __restrict__ C2) {
  const int z = blockIdx.z;
  const float* Ap          = z == 0 ? A0 : z == 1 ? A1 : A2;
  const unsigned short* Bp = z == 0 ? B0 : z == 1 ? B1 : B2;
  const float* bias        = z == 0 ? b0 : z == 1 ? b1 : b2;
  unsigned short* Cp       = z == 0 ? C0 : z == 1 ? C1 : C2;
  gemm_core<true, false>(Ap, Bp, bias, Cp);
}

__global__ __launch_bounds__(512, 2)
void gemm_out(const unsigned short* __restrict__ Ap, const unsigned short* __restrict__ Bp,
              const float* __restrict__ bias, float* __restrict__ Cp) {
  gemm_core<false, true>(Ap, Bp, bias, Cp);
}

// ---------------- block-local attention per (b,h,c) ----------------
__global__ __launch_bounds__(256)
void attn_kernel(const unsigned short* __restrict__ Qp, const unsigned short* __restrict__ Kp,
                 const unsigned short* __restrict__ Vp, unsigned short* __restrict__ Cc) {
  const int bid = blockIdx.x;
  const int c = bid & 63, h = (bid >> 6) & 15, b = bid >> 10;
  const int tid = threadIdx.x;
  const int lane = tid & 63, wave = tid >> 6;
  const int lg = lane >> 4, li = lane & 15;

  __shared__ __align__(16) unsigned short Qs[128 * 64];
  __shared__ __align__(16) unsigned short Ks[128 * 64];
  __shared__ __align__(16) unsigned short Vs[128 * 64];
  __shared__ __align__(16) unsigned short Ps[4][32 * 128];

  const long base = ((long)(b * 8192 + c * 128)) * 1024 + h * 64;
  #pragma unroll
  for (int it = 0; it < 4; ++it) {
    int slot = it * 256 + tid;
    int row = slot >> 3, col = (slot & 7) * 8;
    long g = base + (long)row * 1024 + col;
    gload16(Qp + g, (unsigned char*)Qs + slot * 16);
    gload16(Kp + g, (unsigned char*)Ks + slot * 16);
    gload16(Vp + g, (unsigned char*)Vs + slot * 16);
  }
  __syncthreads();

  // ---- scores: wave w computes rows [w*32, w*32+32) x all 128 key cols ----
  f32x4 sc[2][8];
  #pragma unroll
  for (int m = 0; m < 2; ++m)
    #pragma unroll
    for (int n = 0; n < 8; ++n) sc[m][n] = (f32x4){0.f, 0.f, 0.f, 0.f};

  short8 qf[2][2];
  #pragma unroll
  for (int m = 0; m < 2; ++m)
    #pragma unroll
    for (int ks = 0; ks < 2; ++ks)
      qf[m][ks] = *(const short8*)(Qs + (wave * 32 + m * 16 + li) * 64 + ks * 32 + lg * 8);

  #pragma unroll
  for (int n = 0; n < 8; ++n) {
    short8 kf0 = *(const short8*)(Ks + (n * 16 + li) * 64 + lg * 8);
    short8 kf1 = *(const short8*)(Ks + (n * 16 + li) * 64 + 32 + lg * 8);
    #pragma unroll
    for (int m = 0; m < 2; ++m) {
      sc[m][n] = __builtin_amdgcn_mfma_f32_16x16x32_bf16(qf[m][0], kf0, sc[m][n], 0, 0, 0);
      sc[m][n] = __builtin_amdgcn_mfma_f32_16x16x32_bf16(qf[m][1], kf1, sc[m][n], 0, 0, 0);
    }
  }

  // ---- softmax: row = m*16 + lg*4 + r lives in 16 lanes (same lg) ----
  #pragma unroll
  for (int m = 0; m < 2; ++m)
    #pragma unroll
    for (int r = 0; r < 4; ++r) {
      float mx = sc[m][0][r];
      #pragma unroll
      for (int n = 1; n < 8; ++n) mx = fmaxf(mx, sc[m][n][r]);
      #pragma unroll
      for (int d = 1; d < 16; d <<= 1) mx = fmaxf(mx, __shfl_xor(mx, d));
      float sum = 0.f;
      #pragma unroll
      for (int n = 0; n < 8; ++n) {
        float p = __expf((sc[m][n][r] - mx) * 0.125f);  // scale 1/sqrt(64)
        sc[m][n][r] = p;
        sum += p;
      }
      #pragma unroll
      for (int d = 1; d < 16; d <<= 1) sum += __shfl_xor(sum, d);
      float rinv = 1.f / sum;
      #pragma unroll
      for (int n = 0; n < 8; ++n) sc[m][n][r] *= rinv;
    }

  // ---- P -> LDS (bf16) ----
  #pragma unroll
  for (int m = 0; m < 2; ++m)
    #pragma unroll
    for (int n = 0; n < 8; ++n)
      #pragma unroll
      for (int r = 0; r < 4; ++r)
        Ps[wave][(m * 16 + lg * 4 + r) * 128 + n * 16 + li] = f2bf(sc[m][n][r]);
  __syncthreads();

  // ---- O = P @ V : [32,128] x [128,64] ----
  f32x4 oc[2][4];
  #pragma unroll
  for (int m = 0; m < 2; ++m)
    #pragma unroll
    for (int n = 0; n < 4; ++n) oc[m][n] = (f32x4){0.f, 0.f, 0.f, 0.f};

  #pragma unroll
  for (int ks = 0; ks < 4; ++ks) {
    short8 vf[4];
    #pragma unroll
    for (int n = 0; n < 4; ++n)
      #pragma unroll
      for (int j = 0; j < 8; ++j)
        vf[n][j] = (short)Vs[(ks * 32 + lg * 8 + j) * 64 + n * 16 + li];
    #pragma unroll
    for (int m = 0; m < 2; ++m) {
      short8 pf = *(const short8*)(Ps[wave] + (m * 16 + li) * 128 + ks * 32 + lg * 8);
      #pragma unroll
      for (int n = 0; n < 4; ++n)
        oc[m][n] = __builtin_amdgcn_mfma_f32_16x16x32_bf16(pf, vf[n], oc[m][n], 0, 0, 0);
    }
  }

  // ---- torch-faithful scrambled concat write ----
  #pragma unroll
  for (int m = 0; m < 2; ++m)
    #pragma unroll
    for (int n = 0; n < 4; ++n)
      #pragma unroll
      for (int r = 0; r < 4; ++r) {
        int p = wave * 32 + m * 16 + lg * 4 + r;
        int d = n * 16 + li;
        int s = c * 128 + h * 8 + (p >> 4);
        int colo = (p & 15) * 64 + d;
        Cc[((long)(b * 8192 + s)) * 1024 + colo] = f2bf(oc[m][n][r]);
      }
}

extern "C" void kernel_launch(void* const* d_in, const int* in_sizes, int n_in,
                              void* d_out, int out_size, void* d_ws, size_t ws_size,
                              hipStream_t stream) {
  (void)in_sizes; (void)n_in; (void)out_size; (void)ws_size;
  const float* q  = (const float*)d_in[0];
  const float* k  = (const float*)d_in[1];
  const float* v  = (const float*)d_in[2];
  const float* WQ = (const float*)d_in[3];
  const float* bQ = (const float*)d_in[4];
  const float* WK = (const float*)d_in[5];
  const float* bK = (const float*)d_in[6];
  const float* WV = (const float*)d_in[7];
  const float* bV = (const float*)d_in[8];
  const float* WO = (const float*)d_in[9];
  const float* bO = (const float*)d_in[10];

  // ws layout: Qp | Kp | Vp | Cc (each 64MB bf16) + bf16 weights
  const size_t MN = 32768ull * 1024ull;
  unsigned short* Qp  = (unsigned short*)d_ws;
  unsigned short* Kp  = Qp + MN;
  unsigned short* Vp  = Kp + MN;
  unsigned short* Cc  = Vp + MN;
  unsigned short* WQb = Cc + MN;
  unsigned short* WKb = WQb + (1 << 20);
  unsigned short* WVb = WKb + (1 << 20);
  unsigned short* WOb = WVb + (1 << 20);

  dim3 gw(1024, 1, 4);
  f2b4_kernel<<<gw, 256, 0, stream>>>(WQ, WK, WV, WO, WQb, WKb, WVb, WOb, 1 << 20);

  dim3 gp(4, 128, 3);   // 3 projections batched; 512 blocks per z-slice
  gemm_proj<<<gp, 512, 0, stream>>>(q, k, v, WQb, WKb, WVb, bQ, bK, bV, Qp, Kp, Vp);

  attn_kernel<<<4096, 256, 0, stream>>>(Qp, Kp, Vp, Cc);

  dim3 go(4, 128);
  gemm_out<<<go, 512, 0, stream>>>(Cc, WOb, bO, (float*)d_out);
}

// Round 8
// 547.678 us; speedup vs baseline: 1.4405x; 1.0223x over previous
//
#include <hip/hip_runtime.h>
#include <hip/hip_bf16.h>

// Shapes (fixed): B=4, S=8192, D_MODEL=1024, NHEAD=16, D_K=64, D_CHUNK=128,
// C=64 chunks. M = B*S = 32768 rows for all GEMMs, K=N=1024.

typedef __attribute__((ext_vector_type(8))) short short8;   // 8 bf16 (MFMA A/B frag)
typedef __attribute__((ext_vector_type(4))) float f32x4;    // MFMA C/D frag
typedef __attribute__((ext_vector_type(4))) unsigned short us4;

__device__ __forceinline__ unsigned short f2bf(float f) {
  unsigned u = __float_as_uint(f);
  u += 0x7fffu + ((u >> 16) & 1u);          // RNE round to bf16
  return (unsigned short)(u >> 16);
}

__device__ __forceinline__ void gload16(const void* g, void* l) {
  __builtin_amdgcn_global_load_lds((const __attribute__((address_space(1))) void*)g,
                                   (__attribute__((address_space(3))) void*)l, 16, 0, 0);
}

// -------- fp32 -> bf16: z=0..2 activations (grid-stride), z=3 the 4 weights ----
__global__ __launch_bounds__(256)
void cvt_all_kernel(const float* __restrict__ i0, const float* __restrict__ i1,
                    const float* __restrict__ i2, unsigned short* __restrict__ o0,
                    unsigned short* __restrict__ o1, unsigned short* __restrict__ o2, int n,
                    const float* __restrict__ w0, const float* __restrict__ w1,
                    const float* __restrict__ w2, const float* __restrict__ w3,
                    unsigned short* __restrict__ x0, unsigned short* __restrict__ x1,
                    unsigned short* __restrict__ x2, unsigned short* __restrict__ x3, int wn) {
  const int z = blockIdx.z;
  if (z < 3) {
    const float* in = z == 0 ? i0 : z == 1 ? i1 : i2;
    unsigned short* out = z == 0 ? o0 : z == 1 ? o1 : o2;
    int stride = gridDim.x * 256 * 8;
    for (int i = (blockIdx.x * 256 + threadIdx.x) * 8; i < n; i += stride) {
      f32x4 a = *(const f32x4*)(in + i);
      f32x4 b = *(const f32x4*)(in + i + 4);
      short8 o;
      #pragma unroll
      for (int j = 0; j < 4; ++j) {
        o[j]     = (short)f2bf(a[j]);
        o[4 + j] = (short)f2bf(b[j]);
      }
      *(short8*)(out + i) = o;
    }
  } else {
    int stride = gridDim.x * 256 * 4;
    #pragma unroll
    for (int w = 0; w < 4; ++w) {
      const float* in = w == 0 ? w0 : w == 1 ? w1 : w == 2 ? w2 : w3;
      unsigned short* out = w == 0 ? x0 : w == 1 ? x1 : w == 2 ? x2 : x3;
      for (int i = (blockIdx.x * 256 + threadIdx.x) * 4; i < wn; i += stride) {
        f32x4 x = *(const f32x4*)(in + i);
        us4 o;
        #pragma unroll
        for (int j = 0; j < 4; ++j) o[j] = f2bf(x[j]);
        *(us4*)(out + i) = o;
      }
    }
  }
}

// ---------------- GEMM core: C[M,1024] = A[M,1024](bf16) * B[1024,1024]^T + bias ----
// 256x256 tile, BK=64, 512 threads = 8 waves (2M x 4N), per-wave output 128x64.
// 8-phase schedule (round-6 proven). Per K-tile t: 4 phases x {ds_read subtile;
// stage half-tile; s_barrier; setprio(1); 16 MFMA; setprio(0); s_barrier}.
// A(t+1) staged at P0/P1; B(t+2) at P2/P3; counted vmcnt(4) at P3 drains
// A(t+1), leaves B(t+2)'s 4 loads in flight across the tile boundary.
// vmcnt purity: bias preloaded before the prologue drain; no other VMEM in
// the loop body. T2: LDS dest linear (global_load_lds requirement); XOR
// swizzle g^(row&7) applied to the GLOBAL source granule and identically on
// ds_read (rule 21). Epilogue: coalesced C via wave-private LDS bounce.
template<bool C_F32>
__device__ __forceinline__ void gemm_core(const unsigned short* __restrict__ Ap,
                                          const unsigned short* __restrict__ Bp,
                                          const float* __restrict__ bias,
                                          void* __restrict__ Cp) {
  constexpr int BK = 64, NT = 16;
  const int tid = threadIdx.x;              // 0..511
  const int lane = tid & 63, wave = tid >> 6;
  const int lg = lane >> 4, li = lane & 15;
  const int wr = wave >> 2, wc = wave & 3;  // 2 x 4 wave grid

  // XCD swizzle (nwg = 512, divisible by 8 -> bijective).
  const int orig = blockIdx.y * 4 + blockIdx.x;
  const int wg = (orig & 7) * 64 + (orig >> 3);
  const int bn = wg & 3, bm = wg >> 2;

  const long arow0 = (long)bm * 256;
  const int bcol0 = bn * 256;

  __shared__ __align__(16) unsigned short As[2][256 * BK];  // 64 KB
  __shared__ __align__(16) unsigned short Bs[2][256 * BK];  // 64 KB

  float bv[4];
  #pragma unroll
  for (int n = 0; n < 4; ++n) bv[n] = bias[bcol0 + wc * 64 + n * 16 + li];

  f32x4 acc[8][4];
  #pragma unroll
  for (int m = 0; m < 8; ++m)
    #pragma unroll
    for (int n = 0; n < 4; ++n) acc[m][n] = (f32x4){0.f, 0.f, 0.f, 0.f};

  // Stage one half-tile: h = 0:A-lo 1:A-hi 2:B-lo 3:B-hi of tile u.
  auto stage_half = [&](int u, int h) {
    const int k0 = u * BK;
    const int half = h & 1;
    unsigned short* dst = (h < 2 ? As[u & 1] : Bs[u & 1]) + half * (128 * BK);
    const unsigned short* src = (h < 2) ? Ap : Bp;
    const long rbase = (h < 2) ? (arow0 + half * 128) : (long)(bcol0 + half * 128);
    #pragma unroll
    for (int it = 0; it < 2; ++it) {
      int s = it * 512 + tid;              // 0..1023
      int row = s >> 3;
      int eg = ((s & 7) ^ (row & 7)) * 8;  // pre-swizzled source granule
      gload16(src + (rbase + row) * 1024 + k0 + eg, (unsigned char*)dst + s * 16);
    }
  };

  stage_half(0, 0); stage_half(0, 1); stage_half(0, 2); stage_half(0, 3);
  stage_half(1, 2); stage_half(1, 3);
  asm volatile("s_waitcnt vmcnt(4)" ::: "memory");   // A(0)+B(0) landed
  __builtin_amdgcn_sched_barrier(0);
  __builtin_amdgcn_s_barrier();

  for (int t = 0; t < NT; ++t) {
    const unsigned short* Asb = As[t & 1];
    const unsigned short* Bsb = Bs[t & 1];

    auto LDA = [&](int m, int kk) {
      return *(const short8*)(Asb + (wr * 128 + m * 16 + li) * BK +
                              (((kk * 4 + lg) ^ (li & 7)) * 8));
    };
    auto LDB = [&](int n, int kk) {
      return *(const short8*)(Bsb + (wc * 64 + n * 16 + li) * BK +
                              (((kk * 4 + lg) ^ (li & 7)) * 8));
    };

    short8 b0[4], b1[4];

    // ---- P0 ----
    {
      short8 a0[4];
      #pragma unroll
      for (int i = 0; i < 4; ++i) a0[i] = LDA(i, 0);
      #pragma unroll
      for (int n = 0; n < 4; ++n) b0[n] = LDB(n, 0);
      if (t + 1 < NT) stage_half(t + 1, 0);
      __builtin_amdgcn_s_barrier();
      __builtin_amdgcn_s_setprio(1);
      #pragma unroll
      for (int i = 0; i < 4; ++i)
        #pragma unroll
        for (int n = 0; n < 4; ++n)
          acc[i][n] = __builtin_amdgcn_mfma_f32_16x16x32_bf16(a0[i], b0[n], acc[i][n], 0, 0, 0);
      __builtin_amdgcn_s_setprio(0);
      __builtin_amdgcn_s_barrier();
    }
    // ---- P1 ----
    {
      short8 a1[4];
      #pragma unroll
      for (int i = 0; i < 4; ++i) a1[i] = LDA(i, 1);
      #pragma unroll
      for (int n = 0; n < 4; ++n) b1[n] = LDB(n, 1);
      if (t + 1 < NT) stage_half(t + 1, 1);
      __builtin_amdgcn_s_barrier();
      __builtin_amdgcn_s_setprio(1);
      #pragma unroll
      for (int i = 0; i < 4; ++i)
        #pragma unroll
        for (int n = 0; n < 4; ++n)
          acc[i][n] = __builtin_amdgcn_mfma_f32_16x16x32_bf16(a1[i], b1[n], acc[i][n], 0, 0, 0);
      __builtin_amdgcn_s_setprio(0);
      __builtin_amdgcn_s_barrier();
    }
    // ---- P2 ----
    {
      short8 a2[4];
      #pragma unroll
      for (int i = 0; i < 4; ++i) a2[i] = LDA(4 + i, 0);
      if (t + 2 < NT) stage_half(t + 2, 2);
      __builtin_amdgcn_s_barrier();
      __builtin_amdgcn_s_setprio(1);
      #pragma unroll
      for (int i = 0; i < 4; ++i)
        #pragma unroll
        for (int n = 0; n < 4; ++n)
          acc[4 + i][n] = __builtin_amdgcn_mfma_f32_16x16x32_bf16(a2[i], b0[n], acc[4 + i][n], 0, 0, 0);
      __builtin_amdgcn_s_setprio(0);
      __builtin_amdgcn_s_barrier();
    }
    // ---- P3 ----
    {
      short8 a3[4];
      #pragma unroll
      for (int i = 0; i < 4; ++i) a3[i] = LDA(4 + i, 1);
      if (t + 2 < NT) stage_half(t + 2, 3);
      if (t + 2 < NT) {
        asm volatile("s_waitcnt vmcnt(4)" ::: "memory");   // A(t+1) landed
      } else {
        asm volatile("s_waitcnt vmcnt(0)" ::: "memory");
      }
      __builtin_amdgcn_sched_barrier(0);
      __builtin_amdgcn_s_barrier();                        // tile t+1 ready
      __builtin_amdgcn_s_setprio(1);
      #pragma unroll
      for (int i = 0; i < 4; ++i)
        #pragma unroll
        for (int n = 0; n < 4; ++n)
          acc[4 + i][n] = __builtin_amdgcn_mfma_f32_16x16x32_bf16(a3[i], b1[n], acc[4 + i][n], 0, 0, 0);
      __builtin_amdgcn_s_setprio(0);
      __builtin_amdgcn_s_barrier();
    }
  }

  // ---- epilogue: coalesced C stores via wave-private LDS bounce ----
  float* wsc = (float*)As + wave * (16 * 68);
  #pragma unroll
  for (int m = 0; m < 8; ++m) {
    #pragma unroll
    for (int n = 0; n < 4; ++n)
      #pragma unroll
      for (int r = 0; r < 4; ++r)
        wsc[(lg * 4 + r) * 68 + n * 16 + li] = acc[m][n][r] + bv[n];
    asm volatile("s_waitcnt lgkmcnt(0)" ::: "memory");
    __builtin_amdgcn_sched_barrier(0);
    #pragma unroll
    for (int i = 0; i < 4; ++i) {
      int slot = i * 64 + lane;
      int r = slot >> 4, g = slot & 15;
      f32x4 vv = *(const f32x4*)(wsc + r * 68 + g * 4);
      long grow = arow0 + wr * 128 + m * 16 + r;
      long gcol = bcol0 + wc * 64 + g * 4;
      if constexpr (C_F32) {
        *(f32x4*)((float*)Cp + grow * 1024 + gcol) = vv;
      } else {
        us4 o;
        #pragma unroll
        for (int j = 0; j < 4; ++j) o[j] = f2bf(vv[j]);
        *(us4*)((unsigned short*)Cp + grow * 1024 + gcol) = o;
      }
    }
    asm volatile("s_waitcnt lgkmcnt(0)" ::: "memory");   // reads done before overwrite
    __builtin_amdgcn_sched_barrier(0);
  }
}

// Three projections batched via blockIdx.z (q,k,v are DIFFERENT A matrices).
__global__ __launch_bounds__(512, 2)
void gemm_proj(const unsigned short* __restrict__ A0, const unsigned short* __restrict__ A1,
               const unsigned short* __restrict__ A2,
               const unsigned short* __restrict__ B0, const unsigned short* __restrict__ B1,
               const unsigned short* __restrict__ B2,
               const float* __restrict__ b0, const float* __restrict__ b1,
               const float* __restrict__ b2,
               unsigned short* __restrict__ C0, unsigned short* __restrict__ C1,
               unsigned short* __restrict__ C2) {
  const int z = blockIdx.z;
  const unsigned short* Ap = z == 0 ? A0 : z == 1 ? A1 : A2;
  const unsigned short* Bp = z == 0 ? B0 : z == 1 ? B1 : B2;
  const float* bias        = z == 0 ? b0 : z == 1 ? b1 : b2;
  unsigned short* Cp       = z == 0 ? C0 : z == 1 ? C1 : C2;
  gemm_core<false>(Ap, Bp, bias, Cp);
}

__global__ __launch_bounds__(512, 2)
void gemm_out(const unsigned short* __restrict__ Ap, const unsigned short* __restrict__ Bp,
              const float* __restrict__ bias, float* __restrict__ Cp) {
  gemm_core<true>(Ap, Bp, bias, Cp);
}

// ---------------- block-local attention per (b,h,c) ----------------
// Bank-conflict fixes (T2, same involution discipline as the GEMM):
//  - Qs/Ks: row-major [128][64] read as b128 at row-stride 128B was a 16-way
//    conflict (16 li-lanes -> same bank). Staged with pre-swizzled SOURCE
//    granule ((s&7)^(row&7)) into linear LDS; reads XOR the granule with
//    (li&7)  -> 2-way (free).
//  - Ps: [32][128] rows = 256B stride, b128 reads were 16-way. Writes place
//    col-granule at (col>>3)^(row&7); pf reads XOR (ks*4+lg) with (li&7).
//  - Vs: u16 gather reads are conflict-free by bank arithmetic -> left linear.
__global__ __launch_bounds__(256)
void attn_kernel(const unsigned short* __restrict__ Qp, const unsigned short* __restrict__ Kp,
                 const unsigned short* __restrict__ Vp, unsigned short* __restrict__ Cc) {
  const int bid = blockIdx.x;
  const int c = bid & 63, h = (bid >> 6) & 15, b = bid >> 10;
  const int tid = threadIdx.x;
  const int lane = tid & 63, wave = tid >> 6;
  const int lg = lane >> 4, li = lane & 15;

  __shared__ __align__(16) unsigned short Qs[128 * 64];
  __shared__ __align__(16) unsigned short Ks[128 * 64];
  __shared__ __align__(16) unsigned short Vs[128 * 64];
  __shared__ __align__(16) unsigned short Ps[4][32 * 128];

  const long base = ((long)(b * 8192 + c * 128)) * 1024 + h * 64;
  #pragma unroll
  for (int it = 0; it < 4; ++it) {
    int slot = it * 256 + tid;
    int row = slot >> 3;
    int colsw = ((slot & 7) ^ (row & 7)) * 8;      // swizzled source (Q,K)
    int collin = (slot & 7) * 8;                   // linear source (V)
    gload16(Qp + base + (long)row * 1024 + colsw, (unsigned char*)Qs + slot * 16);
    gload16(Kp + base + (long)row * 1024 + colsw, (unsigned char*)Ks + slot * 16);
    gload16(Vp + base + (long)row * 1024 + collin, (unsigned char*)Vs + slot * 16);
  }
  __syncthreads();

  // ---- scores: wave w computes rows [w*32, w*32+32) x all 128 key cols ----
  f32x4 sc[2][8];
  #pragma unroll
  for (int m = 0; m < 2; ++m)
    #pragma unroll
    for (int n = 0; n < 8; ++n) sc[m][n] = (f32x4){0.f, 0.f, 0.f, 0.f};

  short8 qf[2][2];
  #pragma unroll
  for (int m = 0; m < 2; ++m)
    #pragma unroll
    for (int ks = 0; ks < 2; ++ks)
      qf[m][ks] = *(const short8*)(Qs + (wave * 32 + m * 16 + li) * 64 +
                                   (((ks * 4 + lg) ^ (li & 7)) * 8));

  #pragma unroll
  for (int n = 0; n < 8; ++n) {
    short8 kf0 = *(const short8*)(Ks + (n * 16 + li) * 64 + ((lg ^ (li & 7)) * 8));
    short8 kf1 = *(const short8*)(Ks + (n * 16 + li) * 64 + (((4 + lg) ^ (li & 7)) * 8));
    #pragma unroll
    for (int m = 0; m < 2; ++m) {
      sc[m][n] = __builtin_amdgcn_mfma_f32_16x16x32_bf16(qf[m][0], kf0, sc[m][n], 0, 0, 0);
      sc[m][n] = __builtin_amdgcn_mfma_f32_16x16x32_bf16(qf[m][1], kf1, sc[m][n], 0, 0, 0);
    }
  }

  // ---- softmax: row = m*16 + lg*4 + r lives in 16 lanes (same lg) ----
  #pragma unroll
  for (int m = 0; m < 2; ++m)
    #pragma unroll
    for (int r = 0; r < 4; ++r) {
      float mx = sc[m][0][r];
      #pragma unroll
      for (int n = 1; n < 8; ++n) mx = fmaxf(mx, sc[m][n][r]);
      #pragma unroll
      for (int d = 1; d < 16; d <<= 1) mx = fmaxf(mx, __shfl_xor(mx, d));
      float sum = 0.f;
      #pragma unroll
      for (int n = 0; n < 8; ++n) {
        float p = __expf((sc[m][n][r] - mx) * 0.125f);  // scale 1/sqrt(64)
        sc[m][n][r] = p;
        sum += p;
      }
      #pragma unroll
      for (int d = 1; d < 16; d <<= 1) sum += __shfl_xor(sum, d);
      float rinv = 1.f / sum;
      #pragma unroll
      for (int n = 0; n < 8; ++n) sc[m][n][r] *= rinv;
    }

  // ---- P -> LDS (bf16), granule-swizzled: (row, col) at
  //      row*128 + ((col>>3)^(row&7))*8 + (col&7) ----
  #pragma unroll
  for (int m = 0; m < 2; ++m)
    #pragma unroll
    for (int n = 0; n < 8; ++n)
      #pragma unroll
      for (int r = 0; r < 4; ++r) {
        int row = m * 16 + lg * 4 + r;
        int col = n * 16 + li;
        Ps[wave][row * 128 + (((col >> 3) ^ (row & 7)) * 8) + (col & 7)] = f2bf(sc[m][n][r]);
      }
  __syncthreads();

  // ---- O = P @ V : [32,128] x [128,64] ----
  f32x4 oc[2][4];
  #pragma unroll
  for (int m = 0; m < 2; ++m)
    #pragma unroll
    for (int n = 0; n < 4; ++n) oc[m][n] = (f32x4){0.f, 0.f, 0.f, 0.f};

  #pragma unroll
  for (int ks = 0; ks < 4; ++ks) {
    short8 vf[4];
    #pragma unroll
    for (int n = 0; n < 4; ++n)
      #pragma unroll
      for (int j = 0; j < 8; ++j)
        vf[n][j] = (short)Vs[(ks * 32 + lg * 8 + j) * 64 + n * 16 + li];
    #pragma unroll
    for (int m = 0; m < 2; ++m) {
      short8 pf = *(const short8*)(Ps[wave] + (m * 16 + li) * 128 +
                                   (((ks * 4 + lg) ^ (li & 7)) * 8));
      #pragma unroll
      for (int n = 0; n < 4; ++n)
        oc[m][n] = __builtin_amdgcn_mfma_f32_16x16x32_bf16(pf, vf[n], oc[m][n], 0, 0, 0);
    }
  }

  // ---- torch-faithful scrambled concat write ----
  #pragma unroll
  for (int m = 0; m < 2; ++m)
    #pragma unroll
    for (int n = 0; n < 4; ++n)
      #pragma unroll
      for (int r = 0; r < 4; ++r) {
        int p = wave * 32 + m * 16 + lg * 4 + r;
        int d = n * 16 + li;
        int s = c * 128 + h * 8 + (p >> 4);
        int colo = (p & 15) * 64 + d;
        Cc[((long)(b * 8192 + s)) * 1024 + colo] = f2bf(oc[m][n][r]);
      }
}

extern "C" void kernel_launch(void* const* d_in, const int* in_sizes, int n_in,
                              void* d_out, int out_size, void* d_ws, size_t ws_size,
                              hipStream_t stream) {
  (void)in_sizes; (void)n_in; (void)out_size; (void)ws_size;
  const float* q  = (const float*)d_in[0];
  const float* k  = (const float*)d_in[1];
  const float* v  = (const float*)d_in[2];
  const float* WQ = (const float*)d_in[3];
  const float* bQ = (const float*)d_in[4];
  const float* WK = (const float*)d_in[5];
  const float* bK = (const float*)d_in[6];
  const float* WV = (const float*)d_in[7];
  const float* bV = (const float*)d_in[8];
  const float* WO = (const float*)d_in[9];
  const float* bO = (const float*)d_in[10];

  // ws layout: qb | kb | vb | Qp | Kp | Vp | Cc (each 64MB bf16) + bf16 weights
  const size_t MN = 32768ull * 1024ull;
  unsigned short* qb  = (unsigned short*)d_ws;
  unsigned short* kb  = qb + MN;
  unsigned short* vb  = kb + MN;
  unsigned short* Qp  = vb + MN;
  unsigned short* Kp  = Qp + MN;
  unsigned short* Vp  = Kp + MN;
  unsigned short* Cc  = Vp + MN;
  unsigned short* WQb = Cc + MN;
  unsigned short* WKb = WQb + (1 << 20);
  unsigned short* WVb = WKb + (1 << 20);
  unsigned short* WOb = WVb + (1 << 20);

  const int NA = (int)MN;
  dim3 gc(1024, 1, 4);
  cvt_all_kernel<<<gc, 256, 0, stream>>>(q, k, v, qb, kb, vb, NA,
                                         WQ, WK, WV, WO, WQb, WKb, WVb, WOb, 1 << 20);

  dim3 gp(4, 128, 3);   // 3 projections batched; 512 blocks per z-slice
  gemm_proj<<<gp, 512, 0, stream>>>(qb, kb, vb, WQb, WKb, WVb, bQ, bK, bV, Qp, Kp, Vp);

  attn_kernel<<<4096, 256, 0, stream>>>(Qp, Kp, Vp, Cc);

  dim3 go(4, 128);
  gemm_out<<<go, 512, 0, stream>>>(Cc, WOb, bO, (float*)d_out);
}

// Round 9
// 542.322 us; speedup vs baseline: 1.4547x; 1.0099x over previous
//
#include <hip/hip_runtime.h>
#include <hip/hip_bf16.h>

// Shapes (fixed): B=4, S=8192, D_MODEL=1024, NHEAD=16, D_K=64, D_CHUNK=128,
// C=64 chunks. M = B*S = 32768 rows for all GEMMs, K=N=1024.

typedef __attribute__((ext_vector_type(8))) short short8;   // 8 bf16 (MFMA A/B frag)
typedef __attribute__((ext_vector_type(4))) float f32x4;    // MFMA C/D frag
typedef __attribute__((ext_vector_type(4))) unsigned short us4;

__device__ __forceinline__ unsigned short f2bf(float f) {
  unsigned u = __float_as_uint(f);
  u += 0x7fffu + ((u >> 16) & 1u);          // RNE round to bf16
  return (unsigned short)(u >> 16);
}

__device__ __forceinline__ void gload16(const void* g, void* l) {
  __builtin_amdgcn_global_load_lds((const __attribute__((address_space(1))) void*)g,
                                   (__attribute__((address_space(3))) void*)l, 16, 0, 0);
}

// ---------------- fp32 -> bf16 (4 weight matrices, one dispatch) ----------------
__global__ void f2b4_kernel(const float* __restrict__ i0, const float* __restrict__ i1,
                            const float* __restrict__ i2, const float* __restrict__ i3,
                            unsigned short* __restrict__ o0, unsigned short* __restrict__ o1,
                            unsigned short* __restrict__ o2, unsigned short* __restrict__ o3,
                            int n) {
  const int z = blockIdx.z;
  const float* in = z == 0 ? i0 : z == 1 ? i1 : z == 2 ? i2 : i3;
  unsigned short* out = z == 0 ? o0 : z == 1 ? o1 : z == 2 ? o2 : o3;
  int i = (blockIdx.x * 256 + threadIdx.x) * 4;
  if (i >= n) return;
  f32x4 x = *(const f32x4*)(in + i);
  us4 o;
  #pragma unroll
  for (int j = 0; j < 4; ++j) o[j] = f2bf(x[j]);
  *(us4*)(out + i) = o;
}

// ---------------- GEMM core: C[M,1024] = A[M,1024] * B[1024,1024]^T + bias ----
// 256x256 tile, BK=64, 512 threads = 8 waves (2M x 4N), per-wave output 128x64.
// 8-phase schedule (round-6/8 proven). Per K-tile t: 4 phases x {ds_read
// subtile; stage; s_barrier; setprio(1); 16 MFMA; setprio(0); s_barrier}.
//
// A_F32=false (byte-identical round-8 path): A(t+1) via global_load_lds at
// P0/P1; B(t+2) at P2/P3; counted vmcnt(4) at P3 drains A(t+1), leaves
// B(t+2)'s 4 loads in flight.
//
// A_F32=true (fused fp32->bf16, round-7 correctness + fixed scheduling):
// A(t+1) fp32 -> REGISTERS at P0 (8 dwordx4). The cvt+ds_write runs INSIDE
// the P2/P3 MFMA windows (one half each) — the wave issues VALU/DS while its
// MFMAs execute on the separate matrix pipe (m114), so the conversion is
// hidden instead of serialized between barriers (round-7 mistake). The
// publishing lgkmcnt(0) sits just before P3's closing barrier, after ~32
// MFMAs of drain time. Residency chain (FIFO vmcnt): cvt's data-dep wait on
// areg(t+1) (issued t.P0) drains B(t+1) (issued t-1.P2/P3, older) -> B
// resident for all waves at t+1.P0; B(t+2) (younger) stays in flight. WAR:
// As[(t+1)&1] last read at t-1.P3 before its closing barrier; writes at
// t.P2/P3 are after it. No manual vmcnt in the A_F32 loop.
// T2: LDS dest linear; XOR swizzle g^(row&7) on the GLOBAL source granule
// and identically on ds_read (rule 21). Epilogue: coalesced C stores via
// wave-private LDS bounce.
template<bool A_F32, bool C_F32>
__device__ __forceinline__ void gemm_core(const void* __restrict__ Apv,
                                          const unsigned short* __restrict__ Bp,
                                          const float* __restrict__ bias,
                                          void* __restrict__ Cp) {
  constexpr int BK = 64, NT = 16;
  const int tid = threadIdx.x;              // 0..511
  const int lane = tid & 63, wave = tid >> 6;
  const int lg = lane >> 4, li = lane & 15;
  const int wr = wave >> 2, wc = wave & 3;  // 2 x 4 wave grid

  const unsigned short* Ab = (const unsigned short*)Apv;  // bf16 path
  const float* Af = (const float*)Apv;                    // fp32 path

  // XCD swizzle (nwg = 512, divisible by 8 -> bijective).
  const int orig = blockIdx.y * 4 + blockIdx.x;
  const int wg = (orig & 7) * 64 + (orig >> 3);
  const int bn = wg & 3, bm = wg >> 2;

  const long arow0 = (long)bm * 256;
  const int bcol0 = bn * 256;

  __shared__ __align__(16) unsigned short As[2][256 * BK];  // 64 KB
  __shared__ __align__(16) unsigned short Bs[2][256 * BK];  // 64 KB

  float bv[4];
  #pragma unroll
  for (int n = 0; n < 4; ++n) bv[n] = bias[bcol0 + wc * 64 + n * 16 + li];

  f32x4 acc[8][4];
  #pragma unroll
  for (int m = 0; m < 8; ++m)
    #pragma unroll
    for (int n = 0; n < 4; ++n) acc[m][n] = (f32x4){0.f, 0.f, 0.f, 0.f};

  // Stage one half-tile via global_load_lds: h = 0:A-lo 1:A-hi 2:B-lo 3:B-hi.
  auto stage_half = [&](int u, int h) {
    const int k0 = u * BK;
    const int half = h & 1;
    unsigned short* dst = (h < 2 ? As[u & 1] : Bs[u & 1]) + half * (128 * BK);
    const unsigned short* src = (h < 2) ? Ab : Bp;
    const long rbase = (h < 2) ? (arow0 + half * 128) : (long)(bcol0 + half * 128);
    #pragma unroll
    for (int it = 0; it < 2; ++it) {
      int s = it * 512 + tid;              // 0..1023
      int row = s >> 3;
      int eg = ((s & 7) ^ (row & 7)) * 8;  // pre-swizzled source granule
      gload16(src + (rbase + row) * 1024 + k0 + eg, (unsigned char*)dst + s * 16);
    }
  };

  // fp32-A register staging (A_F32 path). 4 slots/thread; static indexing only.
  f32x4 areg[4][2];
  auto issueA = [&](int u) {
    #pragma unroll
    for (int hf = 0; hf < 2; ++hf)
      #pragma unroll
      for (int it = 0; it < 2; ++it) {
        int s = it * 512 + tid;
        int row = s >> 3;
        int ce = ((s & 7) ^ (row & 7)) * 8;
        const float* p = Af + (arow0 + hf * 128 + row) * 1024 + u * BK + ce;
        areg[hf * 2 + it][0] = *(const f32x4*)p;
        areg[hf * 2 + it][1] = *(const f32x4*)(p + 4);
      }
  };
  // One half (hf passed as literal -> constant-propagated, no dynamic areg idx).
  auto writeA_half = [&](int u, int hf) {
    unsigned short* dstb = As[u & 1] + hf * (128 * BK);
    #pragma unroll
    for (int it = 0; it < 2; ++it) {
      int s = it * 512 + tid;
      short8 o;
      #pragma unroll
      for (int j = 0; j < 4; ++j) {
        o[j]     = (short)f2bf(areg[hf * 2 + it][0][j]);
        o[4 + j] = (short)f2bf(areg[hf * 2 + it][1][j]);
      }
      *(short8*)((unsigned char*)dstb + s * 16) = o;
    }
  };

  // ---- prologue ----
  if constexpr (A_F32) {
    stage_half(0, 2); stage_half(0, 3);   // B(0) first
    issueA(0);                            // A(0) -> regs (younger than B(0))
    stage_half(1, 2); stage_half(1, 3);   // B(1), stays in flight
    writeA_half(0, 0); writeA_half(0, 1); // data-dep drains B(0)+A(0)
    asm volatile("s_waitcnt lgkmcnt(0)" ::: "memory");
    __builtin_amdgcn_sched_barrier(0);
    __builtin_amdgcn_s_barrier();
  } else {
    stage_half(0, 0); stage_half(0, 1); stage_half(0, 2); stage_half(0, 3);
    stage_half(1, 2); stage_half(1, 3);
    asm volatile("s_waitcnt vmcnt(4)" ::: "memory");   // A(0)+B(0) landed
    __builtin_amdgcn_sched_barrier(0);
    __builtin_amdgcn_s_barrier();
  }

  for (int t = 0; t < NT; ++t) {
    const unsigned short* Asb = As[t & 1];
    const unsigned short* Bsb = Bs[t & 1];

    auto LDA = [&](int m, int kk) {
      return *(const short8*)(Asb + (wr * 128 + m * 16 + li) * BK +
                              (((kk * 4 + lg) ^ (li & 7)) * 8));
    };
    auto LDB = [&](int n, int kk) {
      return *(const short8*)(Bsb + (wc * 64 + n * 16 + li) * BK +
                              (((kk * 4 + lg) ^ (li & 7)) * 8));
    };

    short8 b0[4], b1[4];

    // ---- P0 ----
    {
      short8 a0[4];
      #pragma unroll
      for (int i = 0; i < 4; ++i) a0[i] = LDA(i, 0);
      #pragma unroll
      for (int n = 0; n < 4; ++n) b0[n] = LDB(n, 0);
      if constexpr (A_F32) {
        if (t + 1 < NT) issueA(t + 1);
      } else {
        if (t + 1 < NT) stage_half(t + 1, 0);
      }
      __builtin_amdgcn_s_barrier();
      __builtin_amdgcn_s_setprio(1);
      #pragma unroll
      for (int i = 0; i < 4; ++i)
        #pragma unroll
        for (int n = 0; n < 4; ++n)
          acc[i][n] = __builtin_amdgcn_mfma_f32_16x16x32_bf16(a0[i], b0[n], acc[i][n], 0, 0, 0);
      __builtin_amdgcn_s_setprio(0);
      __builtin_amdgcn_s_barrier();
    }
    // ---- P1 ----
    {
      short8 a1[4];
      #pragma unroll
      for (int i = 0; i < 4; ++i) a1[i] = LDA(i, 1);
      #pragma unroll
      for (int n = 0; n < 4; ++n) b1[n] = LDB(n, 1);
      if constexpr (!A_F32) {
        if (t + 1 < NT) stage_half(t + 1, 1);
      }
      __builtin_amdgcn_s_barrier();
      __builtin_amdgcn_s_setprio(1);
      #pragma unroll
      for (int i = 0; i < 4; ++i)
        #pragma unroll
        for (int n = 0; n < 4; ++n)
          acc[i][n] = __builtin_amdgcn_mfma_f32_16x16x32_bf16(a1[i], b1[n], acc[i][n], 0, 0, 0);
      __builtin_amdgcn_s_setprio(0);
      __builtin_amdgcn_s_barrier();
    }
    // ---- P2 ----
    {
      short8 a2[4];
      #pragma unroll
      for (int i = 0; i < 4; ++i) a2[i] = LDA(4 + i, 0);
      if (t + 2 < NT) stage_half(t + 2, 2);
      __builtin_amdgcn_s_barrier();
      __builtin_amdgcn_s_setprio(1);
      #pragma unroll
      for (int i = 0; i < 4; ++i)
        #pragma unroll
        for (int n = 0; n < 4; ++n)
          acc[4 + i][n] = __builtin_amdgcn_mfma_f32_16x16x32_bf16(a2[i], b0[n], acc[4 + i][n], 0, 0, 0);
      if constexpr (A_F32) {            // cvt+write hidden under this MFMA window
        if (t + 1 < NT) writeA_half(t + 1, 0);
      }
      __builtin_amdgcn_s_setprio(0);
      __builtin_amdgcn_s_barrier();
    }
    // ---- P3 ----
    {
      short8 a3[4];
      #pragma unroll
      for (int i = 0; i < 4; ++i) a3[i] = LDA(4 + i, 1);
      if (t + 2 < NT) stage_half(t + 2, 3);
      if constexpr (!A_F32) {
        if (t + 2 < NT) {
          asm volatile("s_waitcnt vmcnt(4)" ::: "memory");   // A(t+1) landed
        } else {
          asm volatile("s_waitcnt vmcnt(0)" ::: "memory");
        }
        __builtin_amdgcn_sched_barrier(0);
      }
      __builtin_amdgcn_s_barrier();                          // tile t+1 ready (bf16 path)
      __builtin_amdgcn_s_setprio(1);
      #pragma unroll
      for (int i = 0; i < 4; ++i)
        #pragma unroll
        for (int n = 0; n < 4; ++n)
          acc[4 + i][n] = __builtin_amdgcn_mfma_f32_16x16x32_bf16(a3[i], b1[n], acc[4 + i][n], 0, 0, 0);
      if constexpr (A_F32) {            // second half under P3's MFMA window
        if (t + 1 < NT) writeA_half(t + 1, 1);
        asm volatile("s_waitcnt lgkmcnt(0)" ::: "memory");   // publish A(t+1)
        __builtin_amdgcn_sched_barrier(0);
      }
      __builtin_amdgcn_s_setprio(0);
      __builtin_amdgcn_s_barrier();                          // closing: A(t+1) visible
    }
  }

  // ---- epilogue: coalesced C stores via wave-private LDS bounce ----
  float* wsc = (float*)As + wave * (16 * 68);
  #pragma unroll
  for (int m = 0; m < 8; ++m) {
    #pragma unroll
    for (int n = 0; n < 4; ++n)
      #pragma unroll
      for (int r = 0; r < 4; ++r)
        wsc[(lg * 4 + r) * 68 + n * 16 + li] = acc[m][n][r] + bv[n];
    asm volatile("s_waitcnt lgkmcnt(0)" ::: "memory");
    __builtin_amdgcn_sched_barrier(0);
    #pragma unroll
    for (int i = 0; i < 4; ++i) {
      int slot = i * 64 + lane;
      int r = slot >> 4, g = slot & 15;
      f32x4 vv = *(const f32x4*)(wsc + r * 68 + g * 4);
      long grow = arow0 + wr * 128 + m * 16 + r;
      long gcol = bcol0 + wc * 64 + g * 4;
      if constexpr (C_F32) {
        *(f32x4*)((float*)Cp + grow * 1024 + gcol) = vv;
      } else {
        us4 o;
        #pragma unroll
        for (int j = 0; j < 4; ++j) o[j] = f2bf(vv[j]);
        *(us4*)((unsigned short*)Cp + grow * 1024 + gcol) = o;
      }
    }
    asm volatile("s_waitcnt lgkmcnt(0)" ::: "memory");   // reads done before overwrite
    __builtin_amdgcn_sched_barrier(0);
  }
}

// Three projections batched via blockIdx.z; A operands are the RAW fp32 inputs.
__global__ __launch_bounds__(512, 2)
void gemm_proj(const float* __restrict__ A0, const float* __restrict__ A1,
               const float* __restrict__ A2,
               const unsigned short* __restrict__ B0, const unsigned short* __restrict__ B1,
               const unsigned short* __restrict__ B2,
               const float* __restrict__ b0, const float* __restrict__ b1,
               const float* __restrict__ b2,
               unsigned short* __restrict__ C0, unsigned short* __restrict__ C1,
               unsigned short* __restrict__ C2) {
  const int z = blockIdx.z;
  const float* Ap          = z == 0 ? A0 : z == 1 ? A1 : A2;
  const unsigned short* Bp = z == 0 ? B0 : z == 1 ? B1 : B2;
  const float* bias        = z == 0 ? b0 : z == 1 ? b1 : b2;
  unsigned short* Cp       = z == 0 ? C0 : z == 1 ? C1 : C2;
  gemm_core<true, false>(Ap, Bp, bias, Cp);
}

__global__ __launch_bounds__(512, 2)
void gemm_out(const unsigned short* __restrict__ Ap, const unsigned short* __restrict__ Bp,
              const float* __restrict__ bias, float* __restrict__ Cp) {
  gemm_core<false, true>(Ap, Bp, bias, Cp);
}

// ---------------- block-local attention per (b,h,c), T2-swizzled (round 8) ----
__global__ __launch_bounds__(256)
void attn_kernel(const unsigned short* __restrict__ Qp, const unsigned short* __restrict__ Kp,
                 const unsigned short* __restrict__ Vp, unsigned short* __restrict__ Cc) {
  const int bid = blockIdx.x;
  const int c = bid & 63, h = (bid >> 6) & 15, b = bid >> 10;
  const int tid = threadIdx.x;
  const int lane = tid & 63, wave = tid >> 6;
  const int lg = lane >> 4, li = lane & 15;

  __shared__ __align__(16) unsigned short Qs[128 * 64];
  __shared__ __align__(16) unsigned short Ks[128 * 64];
  __shared__ __align__(16) unsigned short Vs[128 * 64];
  __shared__ __align__(16) unsigned short Ps[4][32 * 128];

  const long base = ((long)(b * 8192 + c * 128)) * 1024 + h * 64;
  #pragma unroll
  for (int it = 0; it < 4; ++it) {
    int slot = it * 256 + tid;
    int row = slot >> 3;
    int colsw = ((slot & 7) ^ (row & 7)) * 8;      // swizzled source (Q,K)
    int collin = (slot & 7) * 8;                   // linear source (V)
    gload16(Qp + base + (long)row * 1024 + colsw, (unsigned char*)Qs + slot * 16);
    gload16(Kp + base + (long)row * 1024 + colsw, (unsigned char*)Ks + slot * 16);
    gload16(Vp + base + (long)row * 1024 + collin, (unsigned char*)Vs + slot * 16);
  }
  __syncthreads();

  f32x4 sc[2][8];
  #pragma unroll
  for (int m = 0; m < 2; ++m)
    #pragma unroll
    for (int n = 0; n < 8; ++n) sc[m][n] = (f32x4){0.f, 0.f, 0.f, 0.f};

  short8 qf[2][2];
  #pragma unroll
  for (int m = 0; m < 2; ++m)
    #pragma unroll
    for (int ks = 0; ks < 2; ++ks)
      qf[m][ks] = *(const short8*)(Qs + (wave * 32 + m * 16 + li) * 64 +
                                   (((ks * 4 + lg) ^ (li & 7)) * 8));

  #pragma unroll
  for (int n = 0; n < 8; ++n) {
    short8 kf0 = *(const short8*)(Ks + (n * 16 + li) * 64 + ((lg ^ (li & 7)) * 8));
    short8 kf1 = *(const short8*)(Ks + (n * 16 + li) * 64 + (((4 + lg) ^ (li & 7)) * 8));
    #pragma unroll
    for (int m = 0; m < 2; ++m) {
      sc[m][n] = __builtin_amdgcn_mfma_f32_16x16x32_bf16(qf[m][0], kf0, sc[m][n], 0, 0, 0);
      sc[m][n] = __builtin_amdgcn_mfma_f32_16x16x32_bf16(qf[m][1], kf1, sc[m][n], 0, 0, 0);
    }
  }

  #pragma unroll
  for (int m = 0; m < 2; ++m)
    #pragma unroll
    for (int r = 0; r < 4; ++r) {
      float mx = sc[m][0][r];
      #pragma unroll
      for (int n = 1; n < 8; ++n) mx = fmaxf(mx, sc[m][n][r]);
      #pragma unroll
      for (int d = 1; d < 16; d <<= 1) mx = fmaxf(mx, __shfl_xor(mx, d));
      float sum = 0.f;
      #pragma unroll
      for (int n = 0; n < 8; ++n) {
        float p = __expf((sc[m][n][r] - mx) * 0.125f);  // scale 1/sqrt(64)
        sc[m][n][r] = p;
        sum += p;
      }
      #pragma unroll
      for (int d = 1; d < 16; d <<= 1) sum += __shfl_xor(sum, d);
      float rinv = 1.f / sum;
      #pragma unroll
      for (int n = 0; n < 8; ++n) sc[m][n][r] *= rinv;
    }

  #pragma unroll
  for (int m = 0; m < 2; ++m)
    #pragma unroll
    for (int n = 0; n < 8; ++n)
      #pragma unroll
      for (int r = 0; r < 4; ++r) {
        int row = m * 16 + lg * 4 + r;
        int col = n * 16 + li;
        Ps[wave][row * 128 + (((col >> 3) ^ (row & 7)) * 8) + (col & 7)] = f2bf(sc[m][n][r]);
      }
  __syncthreads();

  f32x4 oc[2][4];
  #pragma unroll
  for (int m = 0; m < 2; ++m)
    #pragma unroll
    for (int n = 0; n < 4; ++n) oc[m][n] = (f32x4){0.f, 0.f, 0.f, 0.f};

  #pragma unroll
  for (int ks = 0; ks < 4; ++ks) {
    short8 vf[4];
    #pragma unroll
    for (int n = 0; n < 4; ++n)
      #pragma unroll
      for (int j = 0; j < 8; ++j)
        vf[n][j] = (short)Vs[(ks * 32 + lg * 8 + j) * 64 + n * 16 + li];
    #pragma unroll
    for (int m = 0; m < 2; ++m) {
      short8 pf = *(const short8*)(Ps[wave] + (m * 16 + li) * 128 +
                                   (((ks * 4 + lg) ^ (li & 7)) * 8));
      #pragma unroll
      for (int n = 0; n < 4; ++n)
        oc[m][n] = __builtin_amdgcn_mfma_f32_16x16x32_bf16(pf, vf[n], oc[m][n], 0, 0, 0);
    }
  }

  #pragma unroll
  for (int m = 0; m < 2; ++m)
    #pragma unroll
    for (int n = 0; n < 4; ++n)
      #pragma unroll
      for (int r = 0; r < 4; ++r) {
        int p = wave * 32 + m * 16 + lg * 4 + r;
        int d = n * 16 + li;
        int s = c * 128 + h * 8 + (p >> 4);
        int colo = (p & 15) * 64 + d;
        Cc[((long)(b * 8192 + s)) * 1024 + colo] = f2bf(oc[m][n][r]);
      }
}

extern "C" void kernel_launch(void* const* d_in, const int* in_sizes, int n_in,
                              void* d_out, int out_size, void* d_ws, size_t ws_size,
                              hipStream_t stream) {
  (void)in_sizes; (void)n_in; (void)out_size; (void)ws_size;
  const float* q  = (const float*)d_in[0];
  const float* k  = (const float*)d_in[1];
  const float* v  = (const float*)d_in[2];
  const float* WQ = (const float*)d_in[3];
  const float* bQ = (const float*)d_in[4];
  const float* WK = (const float*)d_in[5];
  const float* bK = (const float*)d_in[6];
  const float* WV = (const float*)d_in[7];
  const float* bV = (const float*)d_in[8];
  const float* WO = (const float*)d_in[9];
  const float* bO = (const float*)d_in[10];

  // ws layout: Qp | Kp | Vp | Cc (each 64MB bf16) + bf16 weights
  const size_t MN = 32768ull * 1024ull;
  unsigned short* Qp  = (unsigned short*)d_ws;
  unsigned short* Kp  = Qp + MN;
  unsigned short* Vp  = Kp + MN;
  unsigned short* Cc  = Vp + MN;
  unsigned short* WQb = Cc + MN;
  unsigned short* WKb = WQb + (1 << 20);
  unsigned short* WVb = WKb + (1 << 20);
  unsigned short* WOb = WVb + (1 << 20);

  dim3 gw(1024, 1, 4);
  f2b4_kernel<<<gw, 256, 0, stream>>>(WQ, WK, WV, WO, WQb, WKb, WVb, WOb, 1 << 20);

  dim3 gp(4, 128, 3);   // 3 projections batched; 512 blocks per z-slice
  gemm_proj<<<gp, 512, 0, stream>>>(q, k, v, WQb, WKb, WVb, bQ, bK, bV, Qp, Kp, Vp);

  attn_kernel<<<4096, 256, 0, stream>>>(Qp, Kp, Vp, Cc);

  dim3 go(4, 128);
  gemm_out<<<go, 512, 0, stream>>>(Cc, WOb, bO, (float*)d_out);
}

// Round 10
// 514.154 us; speedup vs baseline: 1.5344x; 1.0548x over previous
//
#include <hip/hip_runtime.h>
#include <hip/hip_bf16.h>

// Shapes (fixed): B=4, S=8192, D_MODEL=1024, NHEAD=16, D_K=64, D_CHUNK=128,
// C=64 chunks. M = B*S = 32768 rows for all GEMMs, K=N=1024.

typedef __attribute__((ext_vector_type(8))) short short8;   // 8 bf16 (MFMA A/B frag)
typedef __attribute__((ext_vector_type(4))) float f32x4;    // MFMA C/D frag
typedef __attribute__((ext_vector_type(4))) unsigned short us4;
typedef __attribute__((ext_vector_type(4))) unsigned int u32x4;
typedef __attribute__((ext_vector_type(2))) unsigned int u32x2;

__device__ __forceinline__ unsigned short f2bf(float f) {
  unsigned u = __float_as_uint(f);
  u += 0x7fffu + ((u >> 16) & 1u);          // RNE round to bf16
  return (unsigned short)(u >> 16);
}

// HW packed convert: low16 = bf16(lo), high16 = bf16(hi). One VALU op for 2
// elements vs ~6 for manual RNE (T12 primitive; no builtin on gfx950).
__device__ __forceinline__ unsigned cvtpk(float lo, float hi) {
  unsigned r;
  asm("v_cvt_pk_bf16_f32 %0, %1, %2" : "=v"(r) : "v"(lo), "v"(hi));
  return r;
}

__device__ __forceinline__ void gload16(const void* g, void* l) {
  __builtin_amdgcn_global_load_lds((const __attribute__((address_space(1))) void*)g,
                                   (__attribute__((address_space(3))) void*)l, 16, 0, 0);
}

// ---------------- fp32 -> bf16 (4 weight matrices, one dispatch) ----------------
__global__ void f2b4_kernel(const float* __restrict__ i0, const float* __restrict__ i1,
                            const float* __restrict__ i2, const float* __restrict__ i3,
                            unsigned short* __restrict__ o0, unsigned short* __restrict__ o1,
                            unsigned short* __restrict__ o2, unsigned short* __restrict__ o3,
                            int n) {
  const int z = blockIdx.z;
  const float* in = z == 0 ? i0 : z == 1 ? i1 : z == 2 ? i2 : i3;
  unsigned short* out = z == 0 ? o0 : z == 1 ? o1 : z == 2 ? o2 : o3;
  int i = (blockIdx.x * 256 + threadIdx.x) * 4;
  if (i >= n) return;
  f32x4 x = *(const f32x4*)(in + i);
  u32x2 o;
  o[0] = cvtpk(x[0], x[1]);
  o[1] = cvtpk(x[2], x[3]);
  *(u32x2*)(out + i) = o;
}

// ---------------- GEMM core: C[M,1024] = A[M,1024] * B[1024,1024]^T + bias ----
// 256x256 tile, BK=64, 512 threads = 8 waves (2M x 4N), per-wave output 128x64.
// 8-phase schedule. Per K-tile t: 4 phases x {ds_read subtile; stage;
// s_barrier; setprio(1); 16 MFMA; setprio(0); s_barrier}.
//
// A_F32=false (round-8 proven): A(t+1) via global_load_lds at P0/P1; B(t+2)
// at P2/P3; counted vmcnt(4) at P3 drains A(t+1), leaves B(t+2) in flight.
//
// A_F32=true (fused fp32->bf16): A(t+1) fp32 -> regs at P0; cvt+ds_write in
// the P2/P3 MFMA windows (half each) using HW v_cvt_pk_bf16_f32 (16 ops/tile
// vs ~96 manual-RNE VALU — round-9's measured failure term); publishing
// lgkmcnt(0) just before P3's closing barrier. Residency: cvt's data-dep
// wait on areg(t+1) (issued t.P0) drains the older B(t+1) (FIFO); B(t+2)
// (younger) stays in flight. WAR: As[(t+1)&1] last read at t-1.P3 before its
// closing barrier. No manual vmcnt in the A_F32 loop.
// T2: LDS dest linear; XOR swizzle g^(row&7) on the GLOBAL source granule
// and identically on ds_read (rule 21). Epilogue: coalesced C stores via
// wave-private LDS bounce.
template<bool A_F32, bool C_F32>
__device__ __forceinline__ void gemm_core(const void* __restrict__ Apv,
                                          const unsigned short* __restrict__ Bp,
                                          const float* __restrict__ bias,
                                          void* __restrict__ Cp) {
  constexpr int BK = 64, NT = 16;
  const int tid = threadIdx.x;              // 0..511
  const int lane = tid & 63, wave = tid >> 6;
  const int lg = lane >> 4, li = lane & 15;
  const int wr = wave >> 2, wc = wave & 3;  // 2 x 4 wave grid

  const unsigned short* Ab = (const unsigned short*)Apv;  // bf16 path
  const float* Af = (const float*)Apv;                    // fp32 path

  // XCD swizzle (nwg = 512, divisible by 8 -> bijective).
  const int orig = blockIdx.y * 4 + blockIdx.x;
  const int wg = (orig & 7) * 64 + (orig >> 3);
  const int bn = wg & 3, bm = wg >> 2;

  const long arow0 = (long)bm * 256;
  const int bcol0 = bn * 256;

  __shared__ __align__(16) unsigned short As[2][256 * BK];  // 64 KB
  __shared__ __align__(16) unsigned short Bs[2][256 * BK];  // 64 KB

  float bv[4];
  #pragma unroll
  for (int n = 0; n < 4; ++n) bv[n] = bias[bcol0 + wc * 64 + n * 16 + li];

  f32x4 acc[8][4];
  #pragma unroll
  for (int m = 0; m < 8; ++m)
    #pragma unroll
    for (int n = 0; n < 4; ++n) acc[m][n] = (f32x4){0.f, 0.f, 0.f, 0.f};

  // Stage one half-tile via global_load_lds: h = 0:A-lo 1:A-hi 2:B-lo 3:B-hi.
  auto stage_half = [&](int u, int h) {
    const int k0 = u * BK;
    const int half = h & 1;
    unsigned short* dst = (h < 2 ? As[u & 1] : Bs[u & 1]) + half * (128 * BK);
    const unsigned short* src = (h < 2) ? Ab : Bp;
    const long rbase = (h < 2) ? (arow0 + half * 128) : (long)(bcol0 + half * 128);
    #pragma unroll
    for (int it = 0; it < 2; ++it) {
      int s = it * 512 + tid;              // 0..1023
      int row = s >> 3;
      int eg = ((s & 7) ^ (row & 7)) * 8;  // pre-swizzled source granule
      gload16(src + (rbase + row) * 1024 + k0 + eg, (unsigned char*)dst + s * 16);
    }
  };

  // fp32-A register staging (A_F32 path). 4 slots/thread; static indexing only.
  f32x4 areg[4][2];
  auto issueA = [&](int u) {
    #pragma unroll
    for (int hf = 0; hf < 2; ++hf)
      #pragma unroll
      for (int it = 0; it < 2; ++it) {
        int s = it * 512 + tid;
        int row = s >> 3;
        int ce = ((s & 7) ^ (row & 7)) * 8;
        const float* p = Af + (arow0 + hf * 128 + row) * 1024 + u * BK + ce;
        areg[hf * 2 + it][0] = *(const f32x4*)p;
        areg[hf * 2 + it][1] = *(const f32x4*)(p + 4);
      }
  };
  // One half (hf literal -> constant-propagated). 8 cvt_pk + 2 ds_write_b128.
  auto writeA_half = [&](int u, int hf) {
    unsigned short* dstb = As[u & 1] + hf * (128 * BK);
    #pragma unroll
    for (int it = 0; it < 2; ++it) {
      int s = it * 512 + tid;
      u32x4 o;
      o[0] = cvtpk(areg[hf * 2 + it][0][0], areg[hf * 2 + it][0][1]);
      o[1] = cvtpk(areg[hf * 2 + it][0][2], areg[hf * 2 + it][0][3]);
      o[2] = cvtpk(areg[hf * 2 + it][1][0], areg[hf * 2 + it][1][1]);
      o[3] = cvtpk(areg[hf * 2 + it][1][2], areg[hf * 2 + it][1][3]);
      *(u32x4*)((unsigned char*)dstb + s * 16) = o;
    }
  };

  // ---- prologue ----
  if constexpr (A_F32) {
    stage_half(0, 2); stage_half(0, 3);   // B(0) first
    issueA(0);                            // A(0) -> regs (younger than B(0))
    stage_half(1, 2); stage_half(1, 3);   // B(1), stays in flight
    writeA_half(0, 0); writeA_half(0, 1); // data-dep drains B(0)+A(0)
    asm volatile("s_waitcnt lgkmcnt(0)" ::: "memory");
    __builtin_amdgcn_sched_barrier(0);
    __builtin_amdgcn_s_barrier();
  } else {
    stage_half(0, 0); stage_half(0, 1); stage_half(0, 2); stage_half(0, 3);
    stage_half(1, 2); stage_half(1, 3);
    asm volatile("s_waitcnt vmcnt(4)" ::: "memory");   // A(0)+B(0) landed
    __builtin_amdgcn_sched_barrier(0);
    __builtin_amdgcn_s_barrier();
  }

  for (int t = 0; t < NT; ++t) {
    const unsigned short* Asb = As[t & 1];
    const unsigned short* Bsb = Bs[t & 1];

    auto LDA = [&](int m, int kk) {
      return *(const short8*)(Asb + (wr * 128 + m * 16 + li) * BK +
                              (((kk * 4 + lg) ^ (li & 7)) * 8));
    };
    auto LDB = [&](int n, int kk) {
      return *(const short8*)(Bsb + (wc * 64 + n * 16 + li) * BK +
                              (((kk * 4 + lg) ^ (li & 7)) * 8));
    };

    short8 b0[4], b1[4];

    // ---- P0 ----
    {
      short8 a0[4];
      #pragma unroll
      for (int i = 0; i < 4; ++i) a0[i] = LDA(i, 0);
      #pragma unroll
      for (int n = 0; n < 4; ++n) b0[n] = LDB(n, 0);
      if constexpr (A_F32) {
        if (t + 1 < NT) issueA(t + 1);
      } else {
        if (t + 1 < NT) stage_half(t + 1, 0);
      }
      __builtin_amdgcn_s_barrier();
      __builtin_amdgcn_s_setprio(1);
      #pragma unroll
      for (int i = 0; i < 4; ++i)
        #pragma unroll
        for (int n = 0; n < 4; ++n)
          acc[i][n] = __builtin_amdgcn_mfma_f32_16x16x32_bf16(a0[i], b0[n], acc[i][n], 0, 0, 0);
      __builtin_amdgcn_s_setprio(0);
      __builtin_amdgcn_s_barrier();
    }
    // ---- P1 ----
    {
      short8 a1[4];
      #pragma unroll
      for (int i = 0; i < 4; ++i) a1[i] = LDA(i, 1);
      #pragma unroll
      for (int n = 0; n < 4; ++n) b1[n] = LDB(n, 1);
      if constexpr (!A_F32) {
        if (t + 1 < NT) stage_half(t + 1, 1);
      }
      __builtin_amdgcn_s_barrier();
      __builtin_amdgcn_s_setprio(1);
      #pragma unroll
      for (int i = 0; i < 4; ++i)
        #pragma unroll
        for (int n = 0; n < 4; ++n)
          acc[i][n] = __builtin_amdgcn_mfma_f32_16x16x32_bf16(a1[i], b1[n], acc[i][n], 0, 0, 0);
      __builtin_amdgcn_s_setprio(0);
      __builtin_amdgcn_s_barrier();
    }
    // ---- P2 ----
    {
      short8 a2[4];
      #pragma unroll
      for (int i = 0; i < 4; ++i) a2[i] = LDA(4 + i, 0);
      if (t + 2 < NT) stage_half(t + 2, 2);
      __builtin_amdgcn_s_barrier();
      __builtin_amdgcn_s_setprio(1);
      #pragma unroll
      for (int i = 0; i < 4; ++i)
        #pragma unroll
        for (int n = 0; n < 4; ++n)
          acc[4 + i][n] = __builtin_amdgcn_mfma_f32_16x16x32_bf16(a2[i], b0[n], acc[4 + i][n], 0, 0, 0);
      if constexpr (A_F32) {            // 8 cvt_pk + 2 ds_write under this window
        if (t + 1 < NT) writeA_half(t + 1, 0);
      }
      __builtin_amdgcn_s_setprio(0);
      __builtin_amdgcn_s_barrier();
    }
    // ---- P3 ----
    {
      short8 a3[4];
      #pragma unroll
      for (int i = 0; i < 4; ++i) a3[i] = LDA(4 + i, 1);
      if (t + 2 < NT) stage_half(t + 2, 3);
      if constexpr (!A_F32) {
        if (t + 2 < NT) {
          asm volatile("s_waitcnt vmcnt(4)" ::: "memory");   // A(t+1) landed
        } else {
          asm volatile("s_waitcnt vmcnt(0)" ::: "memory");
        }
        __builtin_amdgcn_sched_barrier(0);
      }
      __builtin_amdgcn_s_barrier();                          // tile t+1 ready (bf16 path)
      __builtin_amdgcn_s_setprio(1);
      #pragma unroll
      for (int i = 0; i < 4; ++i)
        #pragma unroll
        for (int n = 0; n < 4; ++n)
          acc[4 + i][n] = __builtin_amdgcn_mfma_f32_16x16x32_bf16(a3[i], b1[n], acc[4 + i][n], 0, 0, 0);
      if constexpr (A_F32) {            // second half under P3's MFMA window
        if (t + 1 < NT) writeA_half(t + 1, 1);
        asm volatile("s_waitcnt lgkmcnt(0)" ::: "memory");   // publish A(t+1)
        __builtin_amdgcn_sched_barrier(0);
      }
      __builtin_amdgcn_s_setprio(0);
      __builtin_amdgcn_s_barrier();                          // closing: A(t+1) visible
    }
  }

  // ---- epilogue: coalesced C stores via wave-private LDS bounce ----
  float* wsc = (float*)As + wave * (16 * 68);
  #pragma unroll
  for (int m = 0; m < 8; ++m) {
    #pragma unroll
    for (int n = 0; n < 4; ++n)
      #pragma unroll
      for (int r = 0; r < 4; ++r)
        wsc[(lg * 4 + r) * 68 + n * 16 + li] = acc[m][n][r] + bv[n];
    asm volatile("s_waitcnt lgkmcnt(0)" ::: "memory");
    __builtin_amdgcn_sched_barrier(0);
    #pragma unroll
    for (int i = 0; i < 4; ++i) {
      int slot = i * 64 + lane;
      int r = slot >> 4, g = slot & 15;
      f32x4 vv = *(const f32x4*)(wsc + r * 68 + g * 4);
      long grow = arow0 + wr * 128 + m * 16 + r;
      long gcol = bcol0 + wc * 64 + g * 4;
      if constexpr (C_F32) {
        *(f32x4*)((float*)Cp + grow * 1024 + gcol) = vv;
      } else {
        u32x2 o;
        o[0] = cvtpk(vv[0], vv[1]);
        o[1] = cvtpk(vv[2], vv[3]);
        *(u32x2*)((unsigned short*)Cp + grow * 1024 + gcol) = o;
      }
    }
    asm volatile("s_waitcnt lgkmcnt(0)" ::: "memory");   // reads done before overwrite
    __builtin_amdgcn_sched_barrier(0);
  }
}

// Three projections batched via blockIdx.z; A operands are the RAW fp32 inputs.
__global__ __launch_bounds__(512, 2)
void gemm_proj(const float* __restrict__ A0, const float* __restrict__ A1,
               const float* __restrict__ A2,
               const unsigned short* __restrict__ B0, const unsigned short* __restrict__ B1,
               const unsigned short* __restrict__ B2,
               const float* __restrict__ b0, const float* __restrict__ b1,
               const float* __restrict__ b2,
               unsigned short* __restrict__ C0, unsigned short* __restrict__ C1,
               unsigned short* __restrict__ C2) {
  const int z = blockIdx.z;
  const float* Ap          = z == 0 ? A0 : z == 1 ? A1 : A2;
  const unsigned short* Bp = z == 0 ? B0 : z == 1 ? B1 : B2;
  const float* bias        = z == 0 ? b0 : z == 1 ? b1 : b2;
  unsigned short* Cp       = z == 0 ? C0 : z == 1 ? C1 : C2;
  gemm_core<true, false>(Ap, Bp, bias, Cp);
}

__global__ __launch_bounds__(512, 2)
void gemm_out(const unsigned short* __restrict__ Ap, const unsigned short* __restrict__ Bp,
              const float* __restrict__ bias, float* __restrict__ Cp) {
  gemm_core<false, true>(Ap, Bp, bias, Cp);
}

// ---------------- block-local attention per (b,h,c), T2-swizzled (round 8) ----
__global__ __launch_bounds__(256)
void attn_kernel(const unsigned short* __restrict__ Qp, const unsigned short* __restrict__ Kp,
                 const unsigned short* __restrict__ Vp, unsigned short* __restrict__ Cc) {
  const int bid = blockIdx.x;
  const int c = bid & 63, h = (bid >> 6) & 15, b = bid >> 10;
  const int tid = threadIdx.x;
  const int lane = tid & 63, wave = tid >> 6;
  const int lg = lane >> 4, li = lane & 15;

  __shared__ __align__(16) unsigned short Qs[128 * 64];
  __shared__ __align__(16) unsigned short Ks[128 * 64];
  __shared__ __align__(16) unsigned short Vs[128 * 64];
  __shared__ __align__(16) unsigned short Ps[4][32 * 128];

  const long base = ((long)(b * 8192 + c * 128)) * 1024 + h * 64;
  #pragma unroll
  for (int it = 0; it < 4; ++it) {
    int slot = it * 256 + tid;
    int row = slot >> 3;
    int colsw = ((slot & 7) ^ (row & 7)) * 8;      // swizzled source (Q,K)
    int collin = (slot & 7) * 8;                   // linear source (V)
    gload16(Qp + base + (long)row * 1024 + colsw, (unsigned char*)Qs + slot * 16);
    gload16(Kp + base + (long)row * 1024 + colsw, (unsigned char*)Ks + slot * 16);
    gload16(Vp + base + (long)row * 1024 + collin, (unsigned char*)Vs + slot * 16);
  }
  __syncthreads();

  f32x4 sc[2][8];
  #pragma unroll
  for (int m = 0; m < 2; ++m)
    #pragma unroll
    for (int n = 0; n < 8; ++n) sc[m][n] = (f32x4){0.f, 0.f, 0.f, 0.f};

  short8 qf[2][2];
  #pragma unroll
  for (int m = 0; m < 2; ++m)
    #pragma unroll
    for (int ks = 0; ks < 2; ++ks)
      qf[m][ks] = *(const short8*)(Qs + (wave * 32 + m * 16 + li) * 64 +
                                   (((ks * 4 + lg) ^ (li & 7)) * 8));

  #pragma unroll
  for (int n = 0; n < 8; ++n) {
    short8 kf0 = *(const short8*)(Ks + (n * 16 + li) * 64 + ((lg ^ (li & 7)) * 8));
    short8 kf1 = *(const short8*)(Ks + (n * 16 + li) * 64 + (((4 + lg) ^ (li & 7)) * 8));
    #pragma unroll
    for (int m = 0; m < 2; ++m) {
      sc[m][n] = __builtin_amdgcn_mfma_f32_16x16x32_bf16(qf[m][0], kf0, sc[m][n], 0, 0, 0);
      sc[m][n] = __builtin_amdgcn_mfma_f32_16x16x32_bf16(qf[m][1], kf1, sc[m][n], 0, 0, 0);
    }
  }

  #pragma unroll
  for (int m = 0; m < 2; ++m)
    #pragma unroll
    for (int r = 0; r < 4; ++r) {
      float mx = sc[m][0][r];
      #pragma unroll
      for (int n = 1; n < 8; ++n) mx = fmaxf(mx, sc[m][n][r]);
      #pragma unroll
      for (int d = 1; d < 16; d <<= 1) mx = fmaxf(mx, __shfl_xor(mx, d));
      float sum = 0.f;
      #pragma unroll
      for (int n = 0; n < 8; ++n) {
        float p = __expf((sc[m][n][r] - mx) * 0.125f);  // scale 1/sqrt(64)
        sc[m][n][r] = p;
        sum += p;
      }
      #pragma unroll
      for (int d = 1; d < 16; d <<= 1) sum += __shfl_xor(sum, d);
      float rinv = 1.f / sum;
      #pragma unroll
      for (int n = 0; n < 8; ++n) sc[m][n][r] *= rinv;
    }

  #pragma unroll
  for (int m = 0; m < 2; ++m)
    #pragma unroll
    for (int n = 0; n < 8; ++n)
      #pragma unroll
      for (int r = 0; r < 4; ++r) {
        int row = m * 16 + lg * 4 + r;
        int col = n * 16 + li;
        Ps[wave][row * 128 + (((col >> 3) ^ (row & 7)) * 8) + (col & 7)] = f2bf(sc[m][n][r]);
      }
  __syncthreads();

  f32x4 oc[2][4];
  #pragma unroll
  for (int m = 0; m < 2; ++m)
    #pragma unroll
    for (int n = 0; n < 4; ++n) oc[m][n] = (f32x4){0.f, 0.f, 0.f, 0.f};

  #pragma unroll
  for (int ks = 0; ks < 4; ++ks) {
    short8 vf[4];
    #pragma unroll
    for (int n = 0; n < 4; ++n)
      #pragma unroll
      for (int j = 0; j < 8; ++j)
        vf[n][j] = (short)Vs[(ks * 32 + lg * 8 + j) * 64 + n * 16 + li];
    #pragma unroll
    for (int m = 0; m < 2; ++m) {
      short8 pf = *(const short8*)(Ps[wave] + (m * 16 + li) * 128 +
                                   (((ks * 4 + lg) ^ (li & 7)) * 8));
      #pragma unroll
      for (int n = 0; n < 4; ++n)
        oc[m][n] = __builtin_amdgcn_mfma_f32_16x16x32_bf16(pf, vf[n], oc[m][n], 0, 0, 0);
    }
  }

  #pragma unroll
  for (int m = 0; m < 2; ++m)
    #pragma unroll
    for (int n = 0; n < 4; ++n)
      #pragma unroll
      for (int r = 0; r < 4; ++r) {
        int p = wave * 32 + m * 16 + lg * 4 + r;
        int d = n * 16 + li;
        int s = c * 128 + h * 8 + (p >> 4);
        int colo = (p & 15) * 64 + d;
        Cc[((long)(b * 8192 + s)) * 1024 + colo] = f2bf(oc[m][n][r]);
      }
}

extern "C" void kernel_launch(void* const* d_in, const int* in_sizes, int n_in,
                              void* d_out, int out_size, void* d_ws, size_t ws_size,
                              hipStream_t stream) {
  (void)in_sizes; (void)n_in; (void)out_size; (void)ws_size;
  const float* q  = (const float*)d_in[0];
  const float* k  = (const float*)d_in[1];
  const float* v  = (const float*)d_in[2];
  const float* WQ = (const float*)d_in[3];
  const float* bQ = (const float*)d_in[4];
  const float* WK = (const float*)d_in[5];
  const float* bK = (const float*)d_in[6];
  const float* WV = (const float*)d_in[7];
  const float* bV = (const float*)d_in[8];
  const float* WO = (const float*)d_in[9];
  const float* bO = (const float*)d_in[10];

  // ws layout: Qp | Kp | Vp | Cc (each 64MB bf16) + bf16 weights
  const size_t MN = 32768ull * 1024ull;
  unsigned short* Qp  = (unsigned short*)d_ws;
  unsigned short* Kp  = Qp + MN;
  unsigned short* Vp  = Kp + MN;
  unsigned short* Cc  = Vp + MN;
  unsigned short* WQb = Cc + MN;
  unsigned short* WKb = WQb + (1 << 20);
  unsigned short* WVb = WKb + (1 << 20);
  unsigned short* WOb = WVb + (1 << 20);

  dim3 gw(1024, 1, 4);
  f2b4_kernel<<<gw, 256, 0, stream>>>(WQ, WK, WV, WO, WQb, WKb, WVb, WOb, 1 << 20);

  dim3 gp(4, 128, 3);   // 3 projections batched; 512 blocks per z-slice
  gemm_proj<<<gp, 512, 0, stream>>>(q, k, v, WQb, WKb, WVb, bQ, bK, bV, Qp, Kp, Vp);

  attn_kernel<<<4096, 256, 0, stream>>>(Qp, Kp, Vp, Cc);

  dim3 go(4, 128);
  gemm_out<<<go, 512, 0, stream>>>(Cc, WOb, bO, (float*)d_out);
}